// Round 4
// baseline (842.234 us; speedup 1.0000x reference)
//
#include <hip/hip_runtime.h>
#include <hip/hip_fp16.h>

#define N_NODES 100000
#define N_EDGES 1600000
#define N_GRAPHS 512
#define FEAT 128
#define EMB 32
#define HALF_CH 16
#define ZROW N_NODES                        // dedicated zero row for padding
#define PADCAP (N_EDGES + 8 * N_NODES)      // pad8 worst-case col slots

typedef unsigned short u16;
typedef float f32x4 __attribute__((ext_vector_type(4)));
typedef unsigned short u16x4 __attribute__((ext_vector_type(4)));

__device__ __forceinline__ int pad8(int d) { return (d + 7) & ~7; }

__device__ __forceinline__ float4 h4_to_f4(u16x4 v) {
  union { unsigned int u; __half2 h; } a, b;
  a.u = (unsigned int)v.x | ((unsigned int)v.y << 16);
  b.u = (unsigned int)v.z | ((unsigned int)v.w << 16);
  float2 f0 = __half22float2(a.h);
  float2 f1 = __half22float2(b.h);
  return make_float4(f0.x, f0.y, f1.x, f1.y);
}

__device__ __forceinline__ u16x4 f4_to_h4(float4 f) {
  union { unsigned int u; __half2 h; } a, b;
  a.h = __float22half2_rn(make_float2(f.x, f.y));
  b.h = __float22half2_rn(make_float2(f.z, f.w));
  u16x4 r;
  r.x = (u16)(a.u & 0xffff); r.y = (u16)(a.u >> 16);
  r.z = (u16)(b.u & 0xffff); r.w = (u16)(b.u >> 16);
  return r;
}

// ---------------- CSR construction ----------------

__global__ __launch_bounds__(256) void k_hist(const int* __restrict__ dst,
                                              int* __restrict__ degcnt) {
  int e = blockIdx.x * 256 + threadIdx.x;
  if (e < N_EDGES) atomicAdd(&degcnt[dst[e]], 1);
}

__global__ __launch_bounds__(256) void k_node_init(const int* __restrict__ degcnt,
                                                   const int* __restrict__ batch,
                                                   float* __restrict__ dis,
                                                   int* __restrict__ gcnt) {
  int i = blockIdx.x * 256 + threadIdx.x;
  if (i < N_NODES) {
    dis[i] = rsqrtf((float)degcnt[i] + 1.0f);
    atomicAdd(&gcnt[batch[i]], 1);
  }
}

// fill padded col slots with ZROW; zero both half-tables' zero rows
__global__ __launch_bounds__(256) void k_colfill(int* __restrict__ col,
                                                 u16* __restrict__ hlo,
                                                 u16* __restrict__ hhi) {
  int i = blockIdx.x * 256 + threadIdx.x;
  if (i < PADCAP) col[i] = ZROW;
  if (i < HALF_CH) {
    hlo[(size_t)ZROW * HALF_CH + i] = 0;
    hhi[(size_t)ZROW * HALF_CH + i] = 0;
  }
}

__global__ __launch_bounds__(256) void k_scanA(const int* __restrict__ degcnt,
                                               int* __restrict__ blocksum) {
  __shared__ int sh[256];
  int t = threadIdx.x;
  int base = blockIdx.x * 1024;
  int s = 0;
#pragma unroll
  for (int j = 0; j < 4; j++) {
    int idx = base + t * 4 + j;
    if (idx < N_NODES) s += pad8(degcnt[idx]);
  }
  sh[t] = s;
  __syncthreads();
  for (int off = 128; off > 0; off >>= 1) {
    if (t < off) sh[t] += sh[t + off];
    __syncthreads();
  }
  if (t == 0) blocksum[blockIdx.x] = sh[0];
}

__global__ __launch_bounds__(128) void k_scanB(const int* __restrict__ blocksum,
                                               int* __restrict__ blockoff,
                                               int* __restrict__ total_out, int nb) {
  __shared__ int sh[128];
  int t = threadIdx.x;
  int v = (t < nb) ? blocksum[t] : 0;
  sh[t] = v;
  __syncthreads();
  for (int off = 1; off < 128; off <<= 1) {
    int add = (t >= off) ? sh[t - off] : 0;
    __syncthreads();
    sh[t] += add;
    __syncthreads();
  }
  if (t < nb) blockoff[t] = sh[t] - v;   // exclusive
  if (t == nb - 1) total_out[0] = sh[t];
}

__global__ __launch_bounds__(256) void k_scanC(const int* __restrict__ degcnt,
                                               const int* __restrict__ blockoff,
                                               int* __restrict__ row_ptr) {
  __shared__ int sh[256];
  int t = threadIdx.x;
  int base = blockIdx.x * 1024;
  int v[4];
#pragma unroll
  for (int j = 0; j < 4; j++) {
    int idx = base + t * 4 + j;
    v[j] = (idx < N_NODES) ? pad8(degcnt[idx]) : 0;
  }
  int tsum = v[0] + v[1] + v[2] + v[3];
  sh[t] = tsum;
  __syncthreads();
  for (int off = 1; off < 256; off <<= 1) {
    int add = (t >= off) ? sh[t - off] : 0;
    __syncthreads();
    sh[t] += add;
    __syncthreads();
  }
  int p = sh[t] - tsum + blockoff[blockIdx.x];
#pragma unroll
  for (int j = 0; j < 4; j++) {
    int idx = base + t * 4 + j;
    if (idx < N_NODES) row_ptr[idx] = p;
    p += v[j];
  }
}

__global__ __launch_bounds__(256) void k_fill(const int* __restrict__ src,
                                              const int* __restrict__ dst,
                                              const int* __restrict__ row_ptr,
                                              int* __restrict__ cursor,
                                              int* __restrict__ col) {
  int e = blockIdx.x * 256 + threadIdx.x;
  if (e < N_EDGES) {
    int d = dst[e];
    int p = atomicAdd(&cursor[d], 1);
    col[row_ptr[d] + p] = src[e];
  }
}

// ---------------- GEMMs (pre-scaled by deg_inv_sqrt, split fp16 output) ----------------

__global__ __launch_bounds__(256) void k_gemm1(const float* __restrict__ x,
                                               const float* __restrict__ W1,
                                               const float* __restrict__ dis,
                                               u16* __restrict__ hlo,
                                               u16* __restrict__ hhi) {
  __shared__ float Wl[FEAT * EMB];  // 16 KB
  int t = threadIdx.x;
  for (int i = t; i < FEAT * EMB; i += 256) Wl[i] = W1[i];
  __syncthreads();
  int row = blockIdx.x * 8 + (t >> 5);
  int c = t & 31;
  const f32x4* xr = (const f32x4*)(x + (size_t)row * FEAT);
  float acc = 0.f;
#pragma unroll
  for (int k4 = 0; k4 < FEAT / 4; ++k4) {
    f32x4 xv = __builtin_nontemporal_load(&xr[k4]);  // one-touch stream: keep L2 clean
    acc = fmaf(xv.x, Wl[(k4 * 4 + 0) * EMB + c], acc);
    acc = fmaf(xv.y, Wl[(k4 * 4 + 1) * EMB + c], acc);
    acc = fmaf(xv.z, Wl[(k4 * 4 + 2) * EMB + c], acc);
    acc = fmaf(xv.w, Wl[(k4 * 4 + 3) * EMB + c], acc);
  }
  u16 hv = __half_as_ushort(__float2half_rn(acc * dis[row]));
  if (c < HALF_CH) hlo[(size_t)row * HALF_CH + c] = hv;
  else             hhi[(size_t)row * HALF_CH + (c - HALF_CH)] = hv;
}

__global__ __launch_bounds__(256) void k_gemm2(const u16* __restrict__ in1,
                                               const float* __restrict__ W2,
                                               const float* __restrict__ dis,
                                               u16* __restrict__ hlo,
                                               u16* __restrict__ hhi) {
  __shared__ float Wl[EMB * EMB];  // 4 KB
  int t = threadIdx.x;
  for (int i = t; i < EMB * EMB; i += 256) Wl[i] = W2[i];
  __syncthreads();
  int row = blockIdx.x * 8 + (t >> 5);
  int c = t & 31;
  const u16x4* xr = (const u16x4*)(in1 + (size_t)row * EMB);
  float acc = 0.f;
#pragma unroll
  for (int q = 0; q < 8; ++q) {
    float4 xv = h4_to_f4(__builtin_nontemporal_load(&xr[q]));
    acc = fmaf(xv.x, Wl[(q * 4 + 0) * EMB + c], acc);
    acc = fmaf(xv.y, Wl[(q * 4 + 1) * EMB + c], acc);
    acc = fmaf(xv.z, Wl[(q * 4 + 2) * EMB + c], acc);
    acc = fmaf(xv.w, Wl[(q * 4 + 3) * EMB + c], acc);
  }
  u16 hv = __half_as_ushort(__float2half_rn(acc * dis[row]));
  if (c < HALF_CH) hlo[(size_t)row * HALF_CH + c] = hv;
  else             hhi[(size_t)row * HALF_CH + (c - HALF_CH)] = hv;
}

// ---------------- Aggregation: wave-per-node, half-channel L2-resident table ----------------

// lane l: g = l>>2 (16 edge slots per chunk), sub = l&3 (4 lanes x ushort4 = 32 B row)
// returns full aggregated quad (self-loop included) replicated across g-groups
__device__ __forceinline__ float4 agg_half(const u16* __restrict__ tab,
                                           const int* __restrict__ row_ptr,
                                           const int* __restrict__ col,
                                           int n, int g, int sub) {
  const u16x4* t4 = (const u16x4*)tab;
  int e0 = row_ptr[n], e1 = row_ptr[n + 1];
  int slots = e1 - e0;                 // multiple of 8
  int nch = (slots + 15) >> 4;         // 16-slot chunks
  float4 acc = make_float4(0.f, 0.f, 0.f, 0.f);
  int cur = ZROW;
  if (g < slots) cur = __builtin_nontemporal_load(&col[e0 + g]);
  for (int i = 0; i < nch; ++i) {
    int nxt = ZROW;
    int off = (i + 1) * 16 + g;
    if (off < slots) nxt = __builtin_nontemporal_load(&col[e0 + off]);
    float4 v = h4_to_f4(t4[(size_t)cur * 4 + sub]);   // cached: table is L2-resident
    acc.x += v.x; acc.y += v.y; acc.z += v.z; acc.w += v.w;
    cur = nxt;
  }
  // reduce across the 16 edge-slot groups
#pragma unroll
  for (int m = 4; m < 64; m <<= 1) {
    acc.x += __shfl_xor(acc.x, m);
    acc.y += __shfl_xor(acc.y, m);
    acc.z += __shfl_xor(acc.z, m);
    acc.w += __shfl_xor(acc.w, m);
  }
  // self-loop (table already dis-scaled), added once post-reduction
  float4 s = h4_to_f4(t4[(size_t)n * 4 + sub]);
  acc.x += s.x; acc.y += s.y; acc.z += s.z; acc.w += s.w;
  return acc;
}

// grid = 2*AB: first AB blocks do channels [0,16), rest do [16,32)
__global__ __launch_bounds__(256) void k_agg1(const u16* __restrict__ hlo,
                                              const u16* __restrict__ hhi,
                                              const int* __restrict__ row_ptr,
                                              const int* __restrict__ col,
                                              const float* __restrict__ dis,
                                              const float* __restrict__ b,
                                              u16* __restrict__ out, int AB) {
  int bx = blockIdx.x;
  int pass = (bx >= AB) ? 1 : 0;
  bx -= pass * AB;
  int t = threadIdx.x;
  int n = bx * 4 + (t >> 6);
  int l = t & 63;
  int g = l >> 2, sub = l & 3;
  const u16* tab = pass ? hhi : hlo;
  float4 acc = agg_half(tab, row_ptr, col, n, g, sub);
  if (g == 0) {
    float d = dis[n];
    float4 bq = ((const float4*)b)[pass * 4 + sub];
    float4 o;
    o.x = fmaxf(fmaf(acc.x, d, bq.x), 0.f);
    o.y = fmaxf(fmaf(acc.y, d, bq.y), 0.f);
    o.z = fmaxf(fmaf(acc.z, d, bq.z), 0.f);
    o.w = fmaxf(fmaf(acc.w, d, bq.w), 0.f);
    u16x4* dstp = (u16x4*)(out + (size_t)n * EMB + pass * HALF_CH);
    __builtin_nontemporal_store(f4_to_h4(o), &dstp[sub]);
  }
}

__global__ __launch_bounds__(256) void k_agg2pool(const u16* __restrict__ hlo,
                                                  const u16* __restrict__ hhi,
                                                  const int* __restrict__ row_ptr,
                                                  const int* __restrict__ col,
                                                  const float* __restrict__ dis,
                                                  const float* __restrict__ b2,
                                                  const float* __restrict__ Wo,
                                                  const int* __restrict__ batch,
                                                  float* __restrict__ gacc, int AB) {
  int bx = blockIdx.x;
  int pass = (bx >= AB) ? 1 : 0;
  bx -= pass * AB;
  int t = threadIdx.x;
  int n = bx * 4 + (t >> 6);
  int l = t & 63;
  int g = l >> 2, sub = l & 3;
  const u16* tab = pass ? hhi : hlo;
  float4 acc = agg_half(tab, row_ptr, col, n, g, sub);
  float d = dis[n];
  float4 bq = ((const float4*)b2)[pass * 4 + sub];
  float4 wq = ((const float4*)Wo)[pass * 4 + sub];
  float p = fmaxf(fmaf(acc.x, d, bq.x), 0.f) * wq.x
          + fmaxf(fmaf(acc.y, d, bq.y), 0.f) * wq.y
          + fmaxf(fmaf(acc.z, d, bq.z), 0.f) * wq.z
          + fmaxf(fmaf(acc.w, d, bq.w), 0.f) * wq.w;
  p += __shfl_xor(p, 1);
  p += __shfl_xor(p, 2);
  if (l == 0) atomicAdd(&gacc[batch[n]], p);
}

__global__ void k_finalize(const float* __restrict__ gacc, const int* __restrict__ gcnt,
                           const float* __restrict__ bo, float* __restrict__ out) {
  int g = blockIdx.x * 256 + threadIdx.x;
  if (g < N_GRAPHS) out[g] = gacc[g] / fmaxf((float)gcnt[g], 1.0f) + bo[0];
}

// ---------------- launch ----------------

extern "C" void kernel_launch(void* const* d_in, const int* in_sizes, int n_in,
                              void* d_out, int out_size, void* d_ws, size_t ws_size,
                              hipStream_t stream) {
  const float* x     = (const float*)d_in[0];
  const int*   ei    = (const int*)d_in[1];   // [2, E]: src then dst
  const int*   batch = (const int*)d_in[2];
  const float* W1    = (const float*)d_in[3];
  const float* b1    = (const float*)d_in[4];
  const float* W2    = (const float*)d_in[5];
  const float* b2    = (const float*)d_in[6];
  const float* Wo    = (const float*)d_in[7];
  const float* bo    = (const float*)d_in[8];
  float* out = (float*)d_out;

  const int* src = ei;
  const int* dst = ei + N_EDGES;

  char* w = (char*)d_ws;
  int*   degcnt  = (int*)w;    w += (size_t)N_NODES * 4;       // zeroed
  int*   cursor  = (int*)w;    w += (size_t)N_NODES * 4;       // zeroed
  float* gacc    = (float*)w;  w += (size_t)N_GRAPHS * 4;      // zeroed
  int*   gcnt    = (int*)w;    w += (size_t)N_GRAPHS * 4;      // zeroed
  size_t zero_bytes = (size_t)(w - (char*)d_ws);
  int*   row_ptr = (int*)w;    w += (size_t)(N_NODES + 4) * 4;
  int*   blocksum= (int*)w;    w += 128 * 4;
  int*   blockoff= (int*)w;    w += 128 * 4;
  int*   col     = (int*)w;    w += (size_t)PADCAP * 4;
  float* dis     = (float*)w;  w += (size_t)N_NODES * 4;
  u16*   h1lo    = (u16*)w;    w += (size_t)(N_NODES + 1) * HALF_CH * 2;
  u16*   h1hi    = (u16*)w;    w += (size_t)(N_NODES + 1) * HALF_CH * 2;
  u16*   out1    = (u16*)w;    w += (size_t)N_NODES * EMB * 2;
  u16*   h2lo    = h1lo;  // dead after agg1 (both passes complete before gemm2)
  u16*   h2hi    = h1hi;  // zero rows persist

  const int EB = (N_EDGES + 255) / 256;    // 6250
  const int NB = (N_NODES + 255) / 256;    // 391
  const int SB = (N_NODES + 1023) / 1024;  // 98
  const int RB = N_NODES / 8;              // 12500 (exact)
  const int AB = N_NODES / 4;              // 25000 node-blocks per pass
  const int CB = (PADCAP + 255) / 256;

  hipMemsetAsync(d_ws, 0, zero_bytes, stream);

  k_hist<<<EB, 256, 0, stream>>>(dst, degcnt);
  k_node_init<<<NB, 256, 0, stream>>>(degcnt, batch, dis, gcnt);
  k_colfill<<<CB, 256, 0, stream>>>(col, h1lo, h1hi);
  k_scanA<<<SB, 256, 0, stream>>>(degcnt, blocksum);
  k_scanB<<<1, 128, 0, stream>>>(blocksum, blockoff, row_ptr + N_NODES, SB);
  k_scanC<<<SB, 256, 0, stream>>>(degcnt, blockoff, row_ptr);
  k_fill<<<EB, 256, 0, stream>>>(src, dst, row_ptr, cursor, col);

  k_gemm1<<<RB, 256, 0, stream>>>(x, W1, dis, h1lo, h1hi);
  k_agg1<<<2 * AB, 256, 0, stream>>>(h1lo, h1hi, row_ptr, col, dis, b1, out1, AB);
  k_gemm2<<<RB, 256, 0, stream>>>(out1, W2, dis, h2lo, h2hi);
  k_agg2pool<<<2 * AB, 256, 0, stream>>>(h2lo, h2hi, row_ptr, col, dis, b2, Wo, batch, gacc, AB);
  k_finalize<<<2, 256, 0, stream>>>(gacc, gcnt, bo, out);
}

// Round 5
// 538.616 us; speedup vs baseline: 1.5637x; 1.5637x over previous
//
#include <hip/hip_runtime.h>
#include <hip/hip_fp16.h>

#define N_NODES 100000
#define N_EDGES 1600000
#define N_GRAPHS 512
#define FEAT 128
#define EMB 32
#define ZROW N_NODES                        // dedicated zero row for padding
#define PADCAP (N_EDGES + 8 * N_NODES)      // pad8 worst-case col slots
#define NCOPY 64                            // privatized pool accumulator copies

typedef unsigned short u16;
typedef float f32x4 __attribute__((ext_vector_type(4)));
typedef unsigned short u16x4 __attribute__((ext_vector_type(4)));

__device__ __forceinline__ int pad8(int d) { return (d + 7) & ~7; }

__device__ __forceinline__ float4 h4_to_f4(u16x4 v) {
  union { unsigned int u; __half2 h; } a, b;
  a.u = (unsigned int)v.x | ((unsigned int)v.y << 16);
  b.u = (unsigned int)v.z | ((unsigned int)v.w << 16);
  float2 f0 = __half22float2(a.h);
  float2 f1 = __half22float2(b.h);
  return make_float4(f0.x, f0.y, f1.x, f1.y);
}

__device__ __forceinline__ u16x4 f4_to_h4(float4 f) {
  union { unsigned int u; __half2 h; } a, b;
  a.h = __float22half2_rn(make_float2(f.x, f.y));
  b.h = __float22half2_rn(make_float2(f.z, f.w));
  u16x4 r;
  r.x = (u16)(a.u & 0xffff); r.y = (u16)(a.u >> 16);
  r.z = (u16)(b.u & 0xffff); r.w = (u16)(b.u >> 16);
  return r;
}

// ---------------- CSR construction ----------------

__global__ __launch_bounds__(256) void k_hist(const int* __restrict__ dst,
                                              int* __restrict__ degcnt) {
  int e = blockIdx.x * 256 + threadIdx.x;
  if (e < N_EDGES) atomicAdd(&degcnt[dst[e]], 1);
}

__global__ __launch_bounds__(256) void k_node_init(const int* __restrict__ degcnt,
                                                   const int* __restrict__ batch,
                                                   float* __restrict__ dis,
                                                   int* __restrict__ gcnt) {
  int i = blockIdx.x * 256 + threadIdx.x;
  if (i < N_NODES) {
    dis[i] = rsqrtf((float)degcnt[i] + 1.0f);
    atomicAdd(&gcnt[batch[i]], 1);
  }
}

// fill padded col slots with ZROW; zero the fp16 zero-row of hs1
__global__ __launch_bounds__(256) void k_colfill(int* __restrict__ col,
                                                 u16* __restrict__ hs1) {
  int i = blockIdx.x * 256 + threadIdx.x;
  if (i < PADCAP) col[i] = ZROW;
  if (i < EMB) hs1[(size_t)ZROW * EMB + i] = 0;
}

__global__ __launch_bounds__(256) void k_scanA(const int* __restrict__ degcnt,
                                               int* __restrict__ blocksum) {
  __shared__ int sh[256];
  int t = threadIdx.x;
  int base = blockIdx.x * 1024;
  int s = 0;
#pragma unroll
  for (int j = 0; j < 4; j++) {
    int idx = base + t * 4 + j;
    if (idx < N_NODES) s += pad8(degcnt[idx]);
  }
  sh[t] = s;
  __syncthreads();
  for (int off = 128; off > 0; off >>= 1) {
    if (t < off) sh[t] += sh[t + off];
    __syncthreads();
  }
  if (t == 0) blocksum[blockIdx.x] = sh[0];
}

__global__ __launch_bounds__(128) void k_scanB(const int* __restrict__ blocksum,
                                               int* __restrict__ blockoff,
                                               int* __restrict__ total_out, int nb) {
  __shared__ int sh[128];
  int t = threadIdx.x;
  int v = (t < nb) ? blocksum[t] : 0;
  sh[t] = v;
  __syncthreads();
  for (int off = 1; off < 128; off <<= 1) {
    int add = (t >= off) ? sh[t - off] : 0;
    __syncthreads();
    sh[t] += add;
    __syncthreads();
  }
  if (t < nb) blockoff[t] = sh[t] - v;   // exclusive
  if (t == nb - 1) total_out[0] = sh[t];
}

__global__ __launch_bounds__(256) void k_scanC(const int* __restrict__ degcnt,
                                               const int* __restrict__ blockoff,
                                               int* __restrict__ row_ptr) {
  __shared__ int sh[256];
  int t = threadIdx.x;
  int base = blockIdx.x * 1024;
  int v[4];
#pragma unroll
  for (int j = 0; j < 4; j++) {
    int idx = base + t * 4 + j;
    v[j] = (idx < N_NODES) ? pad8(degcnt[idx]) : 0;
  }
  int tsum = v[0] + v[1] + v[2] + v[3];
  sh[t] = tsum;
  __syncthreads();
  for (int off = 1; off < 256; off <<= 1) {
    int add = (t >= off) ? sh[t - off] : 0;
    __syncthreads();
    sh[t] += add;
    __syncthreads();
  }
  int p = sh[t] - tsum + blockoff[blockIdx.x];
#pragma unroll
  for (int j = 0; j < 4; j++) {
    int idx = base + t * 4 + j;
    if (idx < N_NODES) row_ptr[idx] = p;
    p += v[j];
  }
}

__global__ __launch_bounds__(256) void k_fill(const int* __restrict__ src,
                                              const int* __restrict__ dst,
                                              const int* __restrict__ row_ptr,
                                              int* __restrict__ cursor,
                                              int* __restrict__ col) {
  int e = blockIdx.x * 256 + threadIdx.x;
  if (e < N_EDGES) {
    int d = dst[e];
    int p = atomicAdd(&cursor[d], 1);
    col[row_ptr[d] + p] = src[e];
  }
}

// ---------------- GEMMs (pre-scaled by deg_inv_sqrt, fp16 output) ----------------

__global__ __launch_bounds__(256) void k_gemm1(const float* __restrict__ x,
                                               const float* __restrict__ W1,
                                               const float* __restrict__ dis,
                                               u16* __restrict__ hs1) {
  __shared__ float Wl[FEAT * EMB];  // 16 KB
  int t = threadIdx.x;
  for (int i = t; i < FEAT * EMB; i += 256) Wl[i] = W1[i];
  __syncthreads();
  int row = blockIdx.x * 8 + (t >> 5);
  int c = t & 31;
  const f32x4* xr = (const f32x4*)(x + (size_t)row * FEAT);
  float acc = 0.f;
#pragma unroll
  for (int k4 = 0; k4 < FEAT / 4; ++k4) {
    f32x4 xv = __builtin_nontemporal_load(&xr[k4]);  // one-touch stream
    acc = fmaf(xv.x, Wl[(k4 * 4 + 0) * EMB + c], acc);
    acc = fmaf(xv.y, Wl[(k4 * 4 + 1) * EMB + c], acc);
    acc = fmaf(xv.z, Wl[(k4 * 4 + 2) * EMB + c], acc);
    acc = fmaf(xv.w, Wl[(k4 * 4 + 3) * EMB + c], acc);
  }
  hs1[row * EMB + c] = __half_as_ushort(__float2half_rn(acc * dis[row]));
}

__global__ __launch_bounds__(256) void k_gemm2(const u16* __restrict__ in1,
                                               const float* __restrict__ W2,
                                               const float* __restrict__ dis,
                                               u16* __restrict__ hs2) {
  __shared__ float Wl[EMB * EMB];  // 4 KB
  int t = threadIdx.x;
  for (int i = t; i < EMB * EMB; i += 256) Wl[i] = W2[i];
  __syncthreads();
  int row = blockIdx.x * 8 + (t >> 5);
  int c = t & 31;
  const u16x4* xr = (const u16x4*)(in1 + (size_t)row * EMB);
  float acc = 0.f;
#pragma unroll
  for (int q = 0; q < 8; ++q) {
    float4 xv = h4_to_f4(xr[q]);
    acc = fmaf(xv.x, Wl[(q * 4 + 0) * EMB + c], acc);
    acc = fmaf(xv.y, Wl[(q * 4 + 1) * EMB + c], acc);
    acc = fmaf(xv.z, Wl[(q * 4 + 2) * EMB + c], acc);
    acc = fmaf(xv.w, Wl[(q * 4 + 3) * EMB + c], acc);
  }
  hs2[row * EMB + c] = __half_as_ushort(__float2half_rn(acc * dis[row]));
}

// ---------------- Aggregation: wave-per-node, 8 rows per gather instruction ----------------

__device__ __forceinline__ float4 agg_row_wide(const u16* __restrict__ hs,
                                               const int* __restrict__ row_ptr,
                                               const int* __restrict__ col,
                                               int n, int g, int sub) {
  const u16x4* hs4 = (const u16x4*)hs;
  int e0 = row_ptr[n], e1 = row_ptr[n + 1];   // multiple of 8 apart
  int nch = (e1 - e0) >> 3;
  int ec = e0 + g;
  float4 acc = make_float4(0.f, 0.f, 0.f, 0.f);
  int s0 = (nch > 0) ? __builtin_nontemporal_load(&col[ec]) : ZROW;
  int s1 = (nch > 1) ? __builtin_nontemporal_load(&col[ec + 8]) : ZROW;
  int i = 0;
  for (; i + 2 <= nch; i += 2) {
    u16x4 va = hs4[(size_t)s0 * 8 + sub];
    u16x4 vb = hs4[(size_t)s1 * 8 + sub];
    int t0 = (i + 2 < nch) ? __builtin_nontemporal_load(&col[ec + (i + 2) * 8]) : ZROW;
    int t1 = (i + 3 < nch) ? __builtin_nontemporal_load(&col[ec + (i + 3) * 8]) : ZROW;
    float4 fa = h4_to_f4(va);
    float4 fb = h4_to_f4(vb);
    acc.x += fa.x + fb.x;
    acc.y += fa.y + fb.y;
    acc.z += fa.z + fb.z;
    acc.w += fa.w + fb.w;
    s0 = t0;
    s1 = t1;
  }
  if (i < nch) {
    float4 fa = h4_to_f4(hs4[(size_t)s0 * 8 + sub]);
    acc.x += fa.x; acc.y += fa.y; acc.z += fa.z; acc.w += fa.w;
  }
#pragma unroll
  for (int m = 8; m < 64; m <<= 1) {
    acc.x += __shfl_xor(acc.x, m);
    acc.y += __shfl_xor(acc.y, m);
    acc.z += __shfl_xor(acc.z, m);
    acc.w += __shfl_xor(acc.w, m);
  }
  // self-loop (hs already dis-scaled); added post-reduction => counted once
  float4 sf = h4_to_f4(hs4[(size_t)n * 8 + sub]);
  acc.x += sf.x; acc.y += sf.y; acc.z += sf.z; acc.w += sf.w;
  return acc;
}

__global__ __launch_bounds__(256) void k_agg1(const u16* __restrict__ hs,
                                              const int* __restrict__ row_ptr,
                                              const int* __restrict__ col,
                                              const float* __restrict__ dis,
                                              const float* __restrict__ b,
                                              u16* __restrict__ out) {
  int t = threadIdx.x;
  int n = blockIdx.x * 4 + (t >> 6);
  int l = t & 63;
  int g = (l >> 3), sub = l & 7;
  float4 acc = agg_row_wide(hs, row_ptr, col, n, g, sub);
  if (g == 0) {
    float d = dis[n];
    float4 bq = ((const float4*)b)[sub];
    float4 o;
    o.x = fmaxf(fmaf(acc.x, d, bq.x), 0.f);
    o.y = fmaxf(fmaf(acc.y, d, bq.y), 0.f);
    o.z = fmaxf(fmaf(acc.z, d, bq.z), 0.f);
    o.w = fmaxf(fmaf(acc.w, d, bq.w), 0.f);
    ((u16x4*)(out + (size_t)n * EMB))[sub] = f4_to_h4(o);
  }
}

// pooling tail: privatized 64-copy accumulator kills same-line atomic contention
__global__ __launch_bounds__(256) void k_agg2pool(const u16* __restrict__ hs,
                                                  const int* __restrict__ row_ptr,
                                                  const int* __restrict__ col,
                                                  const float* __restrict__ dis,
                                                  const float* __restrict__ b2,
                                                  const float* __restrict__ Wo,
                                                  const int* __restrict__ batch,
                                                  float* __restrict__ gaccP) {
  int t = threadIdx.x;
  int n = blockIdx.x * 4 + (t >> 6);
  int l = t & 63;
  int g = (l >> 3), sub = l & 7;
  float4 acc = agg_row_wide(hs, row_ptr, col, n, g, sub);
  float d = dis[n];
  float4 bq = ((const float4*)b2)[sub];
  float4 wq = ((const float4*)Wo)[sub];
  float p = fmaxf(fmaf(acc.x, d, bq.x), 0.f) * wq.x
          + fmaxf(fmaf(acc.y, d, bq.y), 0.f) * wq.y
          + fmaxf(fmaf(acc.z, d, bq.z), 0.f) * wq.z
          + fmaxf(fmaf(acc.w, d, bq.w), 0.f) * wq.w;
  p += __shfl_xor(p, 1);
  p += __shfl_xor(p, 2);
  p += __shfl_xor(p, 4);
  if (l == 0) {
    int copy = blockIdx.x & (NCOPY - 1);   // consecutive blocks -> different copies
    atomicAdd(&gaccP[copy * N_GRAPHS + batch[n]], p);
  }
}

__global__ __launch_bounds__(256) void k_finalize(const float* __restrict__ gaccP,
                                                  const int* __restrict__ gcnt,
                                                  const float* __restrict__ bo,
                                                  float* __restrict__ out) {
  int g = blockIdx.x * 256 + threadIdx.x;
  if (g < N_GRAPHS) {
    float s = 0.f;
#pragma unroll 8
    for (int c = 0; c < NCOPY; ++c) s += gaccP[c * N_GRAPHS + g];
    out[g] = s / fmaxf((float)gcnt[g], 1.0f) + bo[0];
  }
}

// ---------------- launch ----------------

extern "C" void kernel_launch(void* const* d_in, const int* in_sizes, int n_in,
                              void* d_out, int out_size, void* d_ws, size_t ws_size,
                              hipStream_t stream) {
  const float* x     = (const float*)d_in[0];
  const int*   ei    = (const int*)d_in[1];   // [2, E]: src then dst
  const int*   batch = (const int*)d_in[2];
  const float* W1    = (const float*)d_in[3];
  const float* b1    = (const float*)d_in[4];
  const float* W2    = (const float*)d_in[5];
  const float* b2    = (const float*)d_in[6];
  const float* Wo    = (const float*)d_in[7];
  const float* bo    = (const float*)d_in[8];
  float* out = (float*)d_out;

  const int* src = ei;
  const int* dst = ei + N_EDGES;

  char* w = (char*)d_ws;
  int*   degcnt  = (int*)w;    w += (size_t)N_NODES * 4;            // zeroed
  int*   cursor  = (int*)w;    w += (size_t)N_NODES * 4;            // zeroed
  float* gaccP   = (float*)w;  w += (size_t)NCOPY * N_GRAPHS * 4;   // zeroed
  int*   gcnt    = (int*)w;    w += (size_t)N_GRAPHS * 4;           // zeroed
  size_t zero_bytes = (size_t)(w - (char*)d_ws);
  int*   row_ptr = (int*)w;    w += (size_t)(N_NODES + 4) * 4;
  int*   blocksum= (int*)w;    w += 128 * 4;
  int*   blockoff= (int*)w;    w += 128 * 4;
  int*   col     = (int*)w;    w += (size_t)PADCAP * 4;
  float* dis     = (float*)w;  w += (size_t)N_NODES * 4;
  u16*   hs1     = (u16*)w;    w += (size_t)(N_NODES + 1) * EMB * 2;  // +1 zero row
  u16*   out1    = (u16*)w;    w += (size_t)N_NODES * EMB * 2;
  u16*   hs2     = hs1;  // hs1 dead after agg1; zero row persists

  const int EB = (N_EDGES + 255) / 256;    // 6250
  const int NB = (N_NODES + 255) / 256;    // 391
  const int SB = (N_NODES + 1023) / 1024;  // 98
  const int RB = N_NODES / 8;              // 12500 (exact)
  const int AB = N_NODES / 4;              // 25000 wave-per-node blocks
  const int CB = (PADCAP + 255) / 256;

  hipMemsetAsync(d_ws, 0, zero_bytes, stream);

  k_hist<<<EB, 256, 0, stream>>>(dst, degcnt);
  k_node_init<<<NB, 256, 0, stream>>>(degcnt, batch, dis, gcnt);
  k_colfill<<<CB, 256, 0, stream>>>(col, hs1);
  k_scanA<<<SB, 256, 0, stream>>>(degcnt, blocksum);
  k_scanB<<<1, 128, 0, stream>>>(blocksum, blockoff, row_ptr + N_NODES, SB);
  k_scanC<<<SB, 256, 0, stream>>>(degcnt, blockoff, row_ptr);
  k_fill<<<EB, 256, 0, stream>>>(src, dst, row_ptr, cursor, col);

  k_gemm1<<<RB, 256, 0, stream>>>(x, W1, dis, hs1);
  k_agg1<<<AB, 256, 0, stream>>>(hs1, row_ptr, col, dis, b1, out1);
  k_gemm2<<<RB, 256, 0, stream>>>(out1, W2, dis, hs2);
  k_agg2pool<<<AB, 256, 0, stream>>>(hs2, row_ptr, col, dis, b2, Wo, batch, gaccP);
  k_finalize<<<2, 256, 0, stream>>>(gaccP, gcnt, bo, out);
}

// Round 7
// 511.891 us; speedup vs baseline: 1.6453x; 1.0522x over previous
//
#include <hip/hip_runtime.h>
#include <hip/hip_fp16.h>

#define N_NODES 100000
#define N_EDGES 1600000
#define N_GRAPHS 512
#define FEAT 128
#define EMB 32
#define ZROW N_NODES                        // dedicated zero row for padding
#define PADCAP (N_EDGES + 8 * N_NODES)      // pad8 worst-case col slots
#define NCOPY 64                            // privatized pool accumulator copies

typedef unsigned short u16;
typedef float f32x4 __attribute__((ext_vector_type(4)));
typedef unsigned short u16x4 __attribute__((ext_vector_type(4)));
typedef int i32x4 __attribute__((ext_vector_type(4)));

__device__ __forceinline__ int pad8(int d) { return (d + 7) & ~7; }

__device__ __forceinline__ float4 h4_to_f4(u16x4 v) {
  union { unsigned int u; __half2 h; } a, b;
  a.u = (unsigned int)v.x | ((unsigned int)v.y << 16);
  b.u = (unsigned int)v.z | ((unsigned int)v.w << 16);
  float2 f0 = __half22float2(a.h);
  float2 f1 = __half22float2(b.h);
  return make_float4(f0.x, f0.y, f1.x, f1.y);
}

__device__ __forceinline__ u16x4 f4_to_h4(float4 f) {
  union { unsigned int u; __half2 h; } a, b;
  a.h = __float22half2_rn(make_float2(f.x, f.y));
  b.h = __float22half2_rn(make_float2(f.z, f.w));
  u16x4 r;
  r.x = (u16)(a.u & 0xffff); r.y = (u16)(a.u >> 16);
  r.z = (u16)(b.u & 0xffff); r.w = (u16)(b.u >> 16);
  return r;
}

// ---------------- CSR construction ----------------

__global__ __launch_bounds__(256) void k_hist(const int* __restrict__ dst,
                                              int* __restrict__ degcnt) {
  int e = blockIdx.x * 256 + threadIdx.x;
  if (e < N_EDGES) atomicAdd(&degcnt[dst[e]], 1);
}

__global__ __launch_bounds__(256) void k_node_init(const int* __restrict__ degcnt,
                                                   const int* __restrict__ batch,
                                                   float* __restrict__ dis,
                                                   int* __restrict__ gcnt) {
  int i = blockIdx.x * 256 + threadIdx.x;
  if (i < N_NODES) {
    dis[i] = rsqrtf((float)degcnt[i] + 1.0f);
    atomicAdd(&gcnt[batch[i]], 1);
  }
}

// fill padded col slots with ZROW; zero the fp16 zero-row of hs1
__global__ __launch_bounds__(256) void k_colfill(int* __restrict__ col,
                                                 u16* __restrict__ hs1) {
  int i = blockIdx.x * 256 + threadIdx.x;
  if (i < PADCAP) col[i] = ZROW;
  if (i < EMB) hs1[(size_t)ZROW * EMB + i] = 0;
}

__global__ __launch_bounds__(256) void k_scanA(const int* __restrict__ degcnt,
                                               int* __restrict__ blocksum) {
  __shared__ int sh[256];
  int t = threadIdx.x;
  int base = blockIdx.x * 1024;
  int s = 0;
#pragma unroll
  for (int j = 0; j < 4; j++) {
    int idx = base + t * 4 + j;
    if (idx < N_NODES) s += pad8(degcnt[idx]);
  }
  sh[t] = s;
  __syncthreads();
  for (int off = 128; off > 0; off >>= 1) {
    if (t < off) sh[t] += sh[t + off];
    __syncthreads();
  }
  if (t == 0) blocksum[blockIdx.x] = sh[0];
}

__global__ __launch_bounds__(128) void k_scanB(const int* __restrict__ blocksum,
                                               int* __restrict__ blockoff,
                                               int* __restrict__ total_out, int nb) {
  __shared__ int sh[128];
  int t = threadIdx.x;
  int v = (t < nb) ? blocksum[t] : 0;
  sh[t] = v;
  __syncthreads();
  for (int off = 1; off < 128; off <<= 1) {
    int add = (t >= off) ? sh[t - off] : 0;
    __syncthreads();
    sh[t] += add;
    __syncthreads();
  }
  if (t < nb) blockoff[t] = sh[t] - v;   // exclusive
  if (t == nb - 1) total_out[0] = sh[t];
}

__global__ __launch_bounds__(256) void k_scanC(const int* __restrict__ degcnt,
                                               const int* __restrict__ blockoff,
                                               int* __restrict__ row_ptr) {
  __shared__ int sh[256];
  int t = threadIdx.x;
  int base = blockIdx.x * 1024;
  int v[4];
#pragma unroll
  for (int j = 0; j < 4; j++) {
    int idx = base + t * 4 + j;
    v[j] = (idx < N_NODES) ? pad8(degcnt[idx]) : 0;
  }
  int tsum = v[0] + v[1] + v[2] + v[3];
  sh[t] = tsum;
  __syncthreads();
  for (int off = 1; off < 256; off <<= 1) {
    int add = (t >= off) ? sh[t - off] : 0;
    __syncthreads();
    sh[t] += add;
    __syncthreads();
  }
  int p = sh[t] - tsum + blockoff[blockIdx.x];
#pragma unroll
  for (int j = 0; j < 4; j++) {
    int idx = base + t * 4 + j;
    if (idx < N_NODES) row_ptr[idx] = p;
    p += v[j];
  }
}

// Bucketed fill: group g = blockIdx&3 handles dst in [g*25000, (g+1)*25000).
// Writers of any col line are confined to the blocks of one group (~2 XCDs via
// the %-round-robin dispatch heuristic), so partial-line stores merge in L2
// instead of producing one 64 B writeback per 4 B store (R5: WRITE_SIZE=104MB).
__global__ __launch_bounds__(256) void k_fillg(const int* __restrict__ src,
                                               const int* __restrict__ dst,
                                               const int* __restrict__ row_ptr,
                                               int* __restrict__ cursor,
                                               int* __restrict__ col) {
  const int g  = blockIdx.x & 3;
  const int bg = blockIdx.x >> 2;
  const int NPG = 512;                 // blocks per group (grid = 2048)
  const int NQ = N_EDGES / 4;          // 400000 exact
  const i32x4* s4 = (const i32x4*)src;
  const i32x4* d4 = (const i32x4*)dst;
  for (int t = bg * 256 + threadIdx.x; t < NQ; t += NPG * 256) {
    i32x4 d = __builtin_nontemporal_load(&d4[t]);   // NT: keep col window L2-resident
    int b0 = (int)(((unsigned long long)(unsigned)d.x * 171799ull) >> 32);  // /25000
    int b1 = (int)(((unsigned long long)(unsigned)d.y * 171799ull) >> 32);
    int b2 = (int)(((unsigned long long)(unsigned)d.z * 171799ull) >> 32);
    int b3 = (int)(((unsigned long long)(unsigned)d.w * 171799ull) >> 32);
    if ((b0 == g) | (b1 == g) | (b2 == g) | (b3 == g)) {
      i32x4 s = __builtin_nontemporal_load(&s4[t]);
      if (b0 == g) { int p = atomicAdd(&cursor[d.x], 1); col[row_ptr[d.x] + p] = s.x; }
      if (b1 == g) { int p = atomicAdd(&cursor[d.y], 1); col[row_ptr[d.y] + p] = s.y; }
      if (b2 == g) { int p = atomicAdd(&cursor[d.z], 1); col[row_ptr[d.z] + p] = s.z; }
      if (b3 == g) { int p = atomicAdd(&cursor[d.w], 1); col[row_ptr[d.w] + p] = s.w; }
    }
  }
}

// ---------------- GEMMs (pre-scaled by deg_inv_sqrt, fp16 output) ----------------

__global__ __launch_bounds__(256) void k_gemm1(const float* __restrict__ x,
                                               const float* __restrict__ W1,
                                               const float* __restrict__ dis,
                                               u16* __restrict__ hs1) {
  __shared__ float Wl[FEAT * EMB];  // 16 KB
  int t = threadIdx.x;
  for (int i = t; i < FEAT * EMB; i += 256) Wl[i] = W1[i];
  __syncthreads();
  int row = blockIdx.x * 8 + (t >> 5);
  int c = t & 31;
  const f32x4* xr = (const f32x4*)(x + (size_t)row * FEAT);
  float acc = 0.f;
#pragma unroll
  for (int k4 = 0; k4 < FEAT / 4; ++k4) {
    f32x4 xv = __builtin_nontemporal_load(&xr[k4]);  // one-touch stream
    acc = fmaf(xv.x, Wl[(k4 * 4 + 0) * EMB + c], acc);
    acc = fmaf(xv.y, Wl[(k4 * 4 + 1) * EMB + c], acc);
    acc = fmaf(xv.z, Wl[(k4 * 4 + 2) * EMB + c], acc);
    acc = fmaf(xv.w, Wl[(k4 * 4 + 3) * EMB + c], acc);
  }
  hs1[row * EMB + c] = __half_as_ushort(__float2half_rn(acc * dis[row]));
}

__global__ __launch_bounds__(256) void k_gemm2(const u16* __restrict__ in1,
                                               const float* __restrict__ W2,
                                               const float* __restrict__ dis,
                                               u16* __restrict__ hs2) {
  __shared__ float Wl[EMB * EMB];  // 4 KB
  int t = threadIdx.x;
  for (int i = t; i < EMB * EMB; i += 256) Wl[i] = W2[i];
  __syncthreads();
  int row = blockIdx.x * 8 + (t >> 5);
  int c = t & 31;
  const u16x4* xr = (const u16x4*)(in1 + (size_t)row * EMB);
  float acc = 0.f;
#pragma unroll
  for (int q = 0; q < 8; ++q) {
    float4 xv = h4_to_f4(xr[q]);
    acc = fmaf(xv.x, Wl[(q * 4 + 0) * EMB + c], acc);
    acc = fmaf(xv.y, Wl[(q * 4 + 1) * EMB + c], acc);
    acc = fmaf(xv.z, Wl[(q * 4 + 2) * EMB + c], acc);
    acc = fmaf(xv.w, Wl[(q * 4 + 3) * EMB + c], acc);
  }
  hs2[row * EMB + c] = __half_as_ushort(__float2half_rn(acc * dis[row]));
}

// ---------------- Aggregation: wave-per-node, 8 rows per gather instruction ----------------

__device__ __forceinline__ float4 agg_row_wide(const u16* __restrict__ hs,
                                               const int* __restrict__ row_ptr,
                                               const int* __restrict__ col,
                                               int n, int g, int sub) {
  const u16x4* hs4 = (const u16x4*)hs;
  int e0 = row_ptr[n], e1 = row_ptr[n + 1];   // multiple of 8 apart
  int nch = (e1 - e0) >> 3;
  int ec = e0 + g;
  float4 acc = make_float4(0.f, 0.f, 0.f, 0.f);
  int s0 = (nch > 0) ? __builtin_nontemporal_load(&col[ec]) : ZROW;
  int s1 = (nch > 1) ? __builtin_nontemporal_load(&col[ec + 8]) : ZROW;
  int i = 0;
  for (; i + 2 <= nch; i += 2) {
    u16x4 va = hs4[(size_t)s0 * 8 + sub];
    u16x4 vb = hs4[(size_t)s1 * 8 + sub];
    int t0 = (i + 2 < nch) ? __builtin_nontemporal_load(&col[ec + (i + 2) * 8]) : ZROW;
    int t1 = (i + 3 < nch) ? __builtin_nontemporal_load(&col[ec + (i + 3) * 8]) : ZROW;
    float4 fa = h4_to_f4(va);
    float4 fb = h4_to_f4(vb);
    acc.x += fa.x + fb.x;
    acc.y += fa.y + fb.y;
    acc.z += fa.z + fb.z;
    acc.w += fa.w + fb.w;
    s0 = t0;
    s1 = t1;
  }
  if (i < nch) {
    float4 fa = h4_to_f4(hs4[(size_t)s0 * 8 + sub]);
    acc.x += fa.x; acc.y += fa.y; acc.z += fa.z; acc.w += fa.w;
  }
#pragma unroll
  for (int m = 8; m < 64; m <<= 1) {
    acc.x += __shfl_xor(acc.x, m);
    acc.y += __shfl_xor(acc.y, m);
    acc.z += __shfl_xor(acc.z, m);
    acc.w += __shfl_xor(acc.w, m);
  }
  // self-loop (hs already dis-scaled); added post-reduction => counted once
  float4 sf = h4_to_f4(hs4[(size_t)n * 8 + sub]);
  acc.x += sf.x; acc.y += sf.y; acc.z += sf.z; acc.w += sf.w;
  return acc;
}

__global__ __launch_bounds__(256) void k_agg1(const u16* __restrict__ hs,
                                              const int* __restrict__ row_ptr,
                                              const int* __restrict__ col,
                                              const float* __restrict__ dis,
                                              const float* __restrict__ b,
                                              u16* __restrict__ out) {
  int t = threadIdx.x;
  int n = blockIdx.x * 4 + (t >> 6);
  int l = t & 63;
  int g = (l >> 3), sub = l & 7;
  float4 acc = agg_row_wide(hs, row_ptr, col, n, g, sub);
  if (g == 0) {
    float d = dis[n];
    float4 bq = ((const float4*)b)[sub];
    float4 o;
    o.x = fmaxf(fmaf(acc.x, d, bq.x), 0.f);
    o.y = fmaxf(fmaf(acc.y, d, bq.y), 0.f);
    o.z = fmaxf(fmaf(acc.z, d, bq.z), 0.f);
    o.w = fmaxf(fmaf(acc.w, d, bq.w), 0.f);
    ((u16x4*)(out + (size_t)n * EMB))[sub] = f4_to_h4(o);
  }
}

// pooling tail: privatized 64-copy accumulator kills same-line atomic contention
__global__ __launch_bounds__(256) void k_agg2pool(const u16* __restrict__ hs,
                                                  const int* __restrict__ row_ptr,
                                                  const int* __restrict__ col,
                                                  const float* __restrict__ dis,
                                                  const float* __restrict__ b2,
                                                  const float* __restrict__ Wo,
                                                  const int* __restrict__ batch,
                                                  float* __restrict__ gaccP) {
  int t = threadIdx.x;
  int n = blockIdx.x * 4 + (t >> 6);
  int l = t & 63;
  int g = (l >> 3), sub = l & 7;
  float4 acc = agg_row_wide(hs, row_ptr, col, n, g, sub);
  float d = dis[n];
  float4 bq = ((const float4*)b2)[sub];
  float4 wq = ((const float4*)Wo)[sub];
  float p = fmaxf(fmaf(acc.x, d, bq.x), 0.f) * wq.x
          + fmaxf(fmaf(acc.y, d, bq.y), 0.f) * wq.y
          + fmaxf(fmaf(acc.z, d, bq.z), 0.f) * wq.z
          + fmaxf(fmaf(acc.w, d, bq.w), 0.f) * wq.w;
  p += __shfl_xor(p, 1);
  p += __shfl_xor(p, 2);
  p += __shfl_xor(p, 4);
  if (l == 0) {
    int copy = blockIdx.x & (NCOPY - 1);   // consecutive blocks -> different copies
    atomicAdd(&gaccP[copy * N_GRAPHS + batch[n]], p);
  }
}

__global__ __launch_bounds__(256) void k_finalize(const float* __restrict__ gaccP,
                                                  const int* __restrict__ gcnt,
                                                  const float* __restrict__ bo,
                                                  float* __restrict__ out) {
  int g = blockIdx.x * 256 + threadIdx.x;
  if (g < N_GRAPHS) {
    float s = 0.f;
#pragma unroll 8
    for (int c = 0; c < NCOPY; ++c) s += gaccP[c * N_GRAPHS + g];
    out[g] = s / fmaxf((float)gcnt[g], 1.0f) + bo[0];
  }
}

// ---------------- launch ----------------

extern "C" void kernel_launch(void* const* d_in, const int* in_sizes, int n_in,
                              void* d_out, int out_size, void* d_ws, size_t ws_size,
                              hipStream_t stream) {
  const float* x     = (const float*)d_in[0];
  const int*   ei    = (const int*)d_in[1];   // [2, E]: src then dst
  const int*   batch = (const int*)d_in[2];
  const float* W1    = (const float*)d_in[3];
  const float* b1    = (const float*)d_in[4];
  const float* W2    = (const float*)d_in[5];
  const float* b2    = (const float*)d_in[6];
  const float* Wo    = (const float*)d_in[7];
  const float* bo    = (const float*)d_in[8];
  float* out = (float*)d_out;

  const int* src = ei;
  const int* dst = ei + N_EDGES;

  char* w = (char*)d_ws;
  int*   degcnt  = (int*)w;    w += (size_t)N_NODES * 4;            // zeroed
  int*   cursor  = (int*)w;    w += (size_t)N_NODES * 4;            // zeroed
  float* gaccP   = (float*)w;  w += (size_t)NCOPY * N_GRAPHS * 4;   // zeroed
  int*   gcnt    = (int*)w;    w += (size_t)N_GRAPHS * 4;           // zeroed
  size_t zero_bytes = (size_t)(w - (char*)d_ws);
  int*   row_ptr = (int*)w;    w += (size_t)(N_NODES + 4) * 4;
  int*   blocksum= (int*)w;    w += 128 * 4;
  int*   blockoff= (int*)w;    w += 128 * 4;
  int*   col     = (int*)w;    w += (size_t)PADCAP * 4;
  float* dis     = (float*)w;  w += (size_t)N_NODES * 4;
  u16*   hs1     = (u16*)w;    w += (size_t)(N_NODES + 1) * EMB * 2;  // +1 zero row
  u16*   out1    = (u16*)w;    w += (size_t)N_NODES * EMB * 2;
  u16*   hs2     = hs1;  // hs1 dead after agg1; zero row persists

  const int EB = (N_EDGES + 255) / 256;    // 6250
  const int NB = (N_NODES + 255) / 256;    // 391
  const int SB = (N_NODES + 1023) / 1024;  // 98
  const int RB = N_NODES / 8;              // 12500 (exact)
  const int AB = N_NODES / 4;              // 25000 wave-per-node blocks
  const int CB = (PADCAP + 255) / 256;

  (void)hipMemsetAsync(d_ws, 0, zero_bytes, stream);

  k_hist<<<EB, 256, 0, stream>>>(dst, degcnt);
  k_node_init<<<NB, 256, 0, stream>>>(degcnt, batch, dis, gcnt);
  k_colfill<<<CB, 256, 0, stream>>>(col, hs1);
  k_scanA<<<SB, 256, 0, stream>>>(degcnt, blocksum);
  k_scanB<<<1, 128, 0, stream>>>(blocksum, blockoff, row_ptr + N_NODES, SB);
  k_scanC<<<SB, 256, 0, stream>>>(degcnt, blockoff, row_ptr);
  k_fillg<<<2048, 256, 0, stream>>>(src, dst, row_ptr, cursor, col);

  k_gemm1<<<RB, 256, 0, stream>>>(x, W1, dis, hs1);
  k_agg1<<<AB, 256, 0, stream>>>(hs1, row_ptr, col, dis, b1, out1);
  k_gemm2<<<RB, 256, 0, stream>>>(out1, W2, dis, hs2);
  k_agg2pool<<<AB, 256, 0, stream>>>(hs2, row_ptr, col, dis, b2, Wo, batch, gaccP);
  k_finalize<<<2, 256, 0, stream>>>(gaccP, gcnt, bo, out);
}

// Round 8
// 434.729 us; speedup vs baseline: 1.9374x; 1.1775x over previous
//
#include <hip/hip_runtime.h>
#include <hip/hip_fp16.h>

#define N_NODES 100000
#define N_EDGES 1600000
#define N_GRAPHS 512
#define FEAT 128
#define EMB 32
#define ZROW N_NODES                        // dedicated zero row for padding
#define PADCAP (N_EDGES + 8 * N_NODES)      // pad8 worst-case col slots
#define NCOPY 64                            // privatized pool accumulator copies

typedef unsigned short u16;
typedef float f32x4 __attribute__((ext_vector_type(4)));
typedef unsigned short u16x4 __attribute__((ext_vector_type(4)));
typedef int i32x4 __attribute__((ext_vector_type(4)));

__device__ __forceinline__ int pad8(int d) { return (d + 7) & ~7; }

__device__ __forceinline__ float4 h4_to_f4(u16x4 v) {
  union { unsigned int u; __half2 h; } a, b;
  a.u = (unsigned int)v.x | ((unsigned int)v.y << 16);
  b.u = (unsigned int)v.z | ((unsigned int)v.w << 16);
  float2 f0 = __half22float2(a.h);
  float2 f1 = __half22float2(b.h);
  return make_float4(f0.x, f0.y, f1.x, f1.y);
}

__device__ __forceinline__ u16x4 f4_to_h4(float4 f) {
  union { unsigned int u; __half2 h; } a, b;
  a.h = __float22half2_rn(make_float2(f.x, f.y));
  b.h = __float22half2_rn(make_float2(f.z, f.w));
  u16x4 r;
  r.x = (u16)(a.u & 0xffff); r.y = (u16)(a.u >> 16);
  r.z = (u16)(b.u & 0xffff); r.w = (u16)(b.u >> 16);
  return r;
}

// ---------------- CSR construction ----------------

__global__ __launch_bounds__(256) void k_hist(const int* __restrict__ dst,
                                              int* __restrict__ degcnt) {
  int e = blockIdx.x * 256 + threadIdx.x;
  if (e < N_EDGES) atomicAdd(&degcnt[dst[e]], 1);
}

// no atomics: pure elementwise (gcnt handled by k_gcnt binary search)
__global__ __launch_bounds__(256) void k_node_init(const int* __restrict__ degcnt,
                                                   float* __restrict__ dis) {
  int i = blockIdx.x * 256 + threadIdx.x;
  if (i < N_NODES) dis[i] = rsqrtf((float)degcnt[i] + 1.0f);
}

// batch is sorted: per-graph counts via binary search, zero atomics.
// one block of 512 threads; thread g finds first index with batch[idx] >= g.
__global__ __launch_bounds__(512) void k_gcnt(const int* __restrict__ batch,
                                              int* __restrict__ gcnt) {
  __shared__ int first[N_GRAPHS + 1];
  int g = threadIdx.x;
  int lo = 0, hi = N_NODES;
  while (lo < hi) {
    int mid = (lo + hi) >> 1;
    if (batch[mid] < g) lo = mid + 1; else hi = mid;
  }
  first[g] = lo;
  if (g == 0) first[N_GRAPHS] = N_NODES;
  __syncthreads();
  gcnt[g] = first[g + 1] - first[g];
}

// fill padded col slots with ZROW; zero the fp16 zero-row of hs1
__global__ __launch_bounds__(256) void k_colfill(int* __restrict__ col,
                                                 u16* __restrict__ hs1) {
  int i = blockIdx.x * 256 + threadIdx.x;
  if (i < PADCAP) col[i] = ZROW;
  if (i < EMB) hs1[(size_t)ZROW * EMB + i] = 0;
}

__global__ __launch_bounds__(256) void k_scanA(const int* __restrict__ degcnt,
                                               int* __restrict__ blocksum) {
  __shared__ int sh[256];
  int t = threadIdx.x;
  int base = blockIdx.x * 1024;
  int s = 0;
#pragma unroll
  for (int j = 0; j < 4; j++) {
    int idx = base + t * 4 + j;
    if (idx < N_NODES) s += pad8(degcnt[idx]);
  }
  sh[t] = s;
  __syncthreads();
  for (int off = 128; off > 0; off >>= 1) {
    if (t < off) sh[t] += sh[t + off];
    __syncthreads();
  }
  if (t == 0) blocksum[blockIdx.x] = sh[0];
}

__global__ __launch_bounds__(128) void k_scanB(const int* __restrict__ blocksum,
                                               int* __restrict__ blockoff,
                                               int* __restrict__ total_out, int nb) {
  __shared__ int sh[128];
  int t = threadIdx.x;
  int v = (t < nb) ? blocksum[t] : 0;
  sh[t] = v;
  __syncthreads();
  for (int off = 1; off < 128; off <<= 1) {
    int add = (t >= off) ? sh[t - off] : 0;
    __syncthreads();
    sh[t] += add;
    __syncthreads();
  }
  if (t < nb) blockoff[t] = sh[t] - v;   // exclusive
  if (t == nb - 1) total_out[0] = sh[t];
}

__global__ __launch_bounds__(256) void k_scanC(const int* __restrict__ degcnt,
                                               const int* __restrict__ blockoff,
                                               int* __restrict__ row_ptr) {
  __shared__ int sh[256];
  int t = threadIdx.x;
  int base = blockIdx.x * 1024;
  int v[4];
#pragma unroll
  for (int j = 0; j < 4; j++) {
    int idx = base + t * 4 + j;
    v[j] = (idx < N_NODES) ? pad8(degcnt[idx]) : 0;
  }
  int tsum = v[0] + v[1] + v[2] + v[3];
  sh[t] = tsum;
  __syncthreads();
  for (int off = 1; off < 256; off <<= 1) {
    int add = (t >= off) ? sh[t - off] : 0;
    __syncthreads();
    sh[t] += add;
    __syncthreads();
  }
  int p = sh[t] - tsum + blockoff[blockIdx.x];
#pragma unroll
  for (int j = 0; j < 4; j++) {
    int idx = base + t * 4 + j;
    if (idx < N_NODES) row_ptr[idx] = p;
    p += v[j];
  }
}

// Bucketed fill: group g = blockIdx&3 handles dst in [g*25000, (g+1)*25000).
__global__ __launch_bounds__(256) void k_fillg(const int* __restrict__ src,
                                               const int* __restrict__ dst,
                                               const int* __restrict__ row_ptr,
                                               int* __restrict__ cursor,
                                               int* __restrict__ col) {
  const int g  = blockIdx.x & 3;
  const int bg = blockIdx.x >> 2;
  const int NPG = 512;                 // blocks per group (grid = 2048)
  const int NQ = N_EDGES / 4;          // 400000 exact
  const i32x4* s4 = (const i32x4*)src;
  const i32x4* d4 = (const i32x4*)dst;
  for (int t = bg * 256 + threadIdx.x; t < NQ; t += NPG * 256) {
    i32x4 d = __builtin_nontemporal_load(&d4[t]);   // NT: keep col window L2-resident
    int b0 = (int)(((unsigned long long)(unsigned)d.x * 171799ull) >> 32);  // /25000
    int b1 = (int)(((unsigned long long)(unsigned)d.y * 171799ull) >> 32);
    int b2 = (int)(((unsigned long long)(unsigned)d.z * 171799ull) >> 32);
    int b3 = (int)(((unsigned long long)(unsigned)d.w * 171799ull) >> 32);
    if ((b0 == g) | (b1 == g) | (b2 == g) | (b3 == g)) {
      i32x4 s = __builtin_nontemporal_load(&s4[t]);
      if (b0 == g) { int p = atomicAdd(&cursor[d.x], 1); col[row_ptr[d.x] + p] = s.x; }
      if (b1 == g) { int p = atomicAdd(&cursor[d.y], 1); col[row_ptr[d.y] + p] = s.y; }
      if (b2 == g) { int p = atomicAdd(&cursor[d.z], 1); col[row_ptr[d.z] + p] = s.z; }
      if (b3 == g) { int p = atomicAdd(&cursor[d.w], 1); col[row_ptr[d.w] + p] = s.w; }
    }
  }
}

// ---------------- GEMMs (pre-scaled by deg_inv_sqrt, fp16 output) ----------------

__global__ __launch_bounds__(256) void k_gemm1(const float* __restrict__ x,
                                               const float* __restrict__ W1,
                                               const float* __restrict__ dis,
                                               u16* __restrict__ hs1) {
  __shared__ float Wl[FEAT * EMB];  // 16 KB
  int t = threadIdx.x;
  for (int i = t; i < FEAT * EMB; i += 256) Wl[i] = W1[i];
  __syncthreads();
  int row = blockIdx.x * 8 + (t >> 5);
  int c = t & 31;
  const f32x4* xr = (const f32x4*)(x + (size_t)row * FEAT);
  float acc = 0.f;
#pragma unroll
  for (int k4 = 0; k4 < FEAT / 4; ++k4) {
    f32x4 xv = __builtin_nontemporal_load(&xr[k4]);  // one-touch stream
    acc = fmaf(xv.x, Wl[(k4 * 4 + 0) * EMB + c], acc);
    acc = fmaf(xv.y, Wl[(k4 * 4 + 1) * EMB + c], acc);
    acc = fmaf(xv.z, Wl[(k4 * 4 + 2) * EMB + c], acc);
    acc = fmaf(xv.w, Wl[(k4 * 4 + 3) * EMB + c], acc);
  }
  hs1[row * EMB + c] = __half_as_ushort(__float2half_rn(acc * dis[row]));
}

__global__ __launch_bounds__(256) void k_gemm2(const u16* __restrict__ in1,
                                               const float* __restrict__ W2,
                                               const float* __restrict__ dis,
                                               u16* __restrict__ hs2) {
  __shared__ float Wl[EMB * EMB];  // 4 KB
  int t = threadIdx.x;
  for (int i = t; i < EMB * EMB; i += 256) Wl[i] = W2[i];
  __syncthreads();
  int row = blockIdx.x * 8 + (t >> 5);
  int c = t & 31;
  const u16x4* xr = (const u16x4*)(in1 + (size_t)row * EMB);
  float acc = 0.f;
#pragma unroll
  for (int q = 0; q < 8; ++q) {
    float4 xv = h4_to_f4(xr[q]);
    acc = fmaf(xv.x, Wl[(q * 4 + 0) * EMB + c], acc);
    acc = fmaf(xv.y, Wl[(q * 4 + 1) * EMB + c], acc);
    acc = fmaf(xv.z, Wl[(q * 4 + 2) * EMB + c], acc);
    acc = fmaf(xv.w, Wl[(q * 4 + 3) * EMB + c], acc);
  }
  hs2[row * EMB + c] = __half_as_ushort(__float2half_rn(acc * dis[row]));
}

// ---------------- Aggregation: wave-per-node, 8 rows per gather instruction ----------------

__device__ __forceinline__ float4 agg_row_wide(const u16* __restrict__ hs,
                                               const int* __restrict__ row_ptr,
                                               const int* __restrict__ col,
                                               int n, int g, int sub) {
  const u16x4* hs4 = (const u16x4*)hs;
  int e0 = row_ptr[n], e1 = row_ptr[n + 1];   // multiple of 8 apart
  int nch = (e1 - e0) >> 3;
  int ec = e0 + g;
  float4 acc = make_float4(0.f, 0.f, 0.f, 0.f);
  int s0 = (nch > 0) ? __builtin_nontemporal_load(&col[ec]) : ZROW;
  int s1 = (nch > 1) ? __builtin_nontemporal_load(&col[ec + 8]) : ZROW;
  int i = 0;
  for (; i + 2 <= nch; i += 2) {
    u16x4 va = hs4[(size_t)s0 * 8 + sub];
    u16x4 vb = hs4[(size_t)s1 * 8 + sub];
    int t0 = (i + 2 < nch) ? __builtin_nontemporal_load(&col[ec + (i + 2) * 8]) : ZROW;
    int t1 = (i + 3 < nch) ? __builtin_nontemporal_load(&col[ec + (i + 3) * 8]) : ZROW;
    float4 fa = h4_to_f4(va);
    float4 fb = h4_to_f4(vb);
    acc.x += fa.x + fb.x;
    acc.y += fa.y + fb.y;
    acc.z += fa.z + fb.z;
    acc.w += fa.w + fb.w;
    s0 = t0;
    s1 = t1;
  }
  if (i < nch) {
    float4 fa = h4_to_f4(hs4[(size_t)s0 * 8 + sub]);
    acc.x += fa.x; acc.y += fa.y; acc.z += fa.z; acc.w += fa.w;
  }
#pragma unroll
  for (int m = 8; m < 64; m <<= 1) {
    acc.x += __shfl_xor(acc.x, m);
    acc.y += __shfl_xor(acc.y, m);
    acc.z += __shfl_xor(acc.z, m);
    acc.w += __shfl_xor(acc.w, m);
  }
  // self-loop (hs already dis-scaled); added post-reduction => counted once
  float4 sf = h4_to_f4(hs4[(size_t)n * 8 + sub]);
  acc.x += sf.x; acc.y += sf.y; acc.z += sf.z; acc.w += sf.w;
  return acc;
}

__global__ __launch_bounds__(256) void k_agg1(const u16* __restrict__ hs,
                                              const int* __restrict__ row_ptr,
                                              const int* __restrict__ col,
                                              const float* __restrict__ dis,
                                              const float* __restrict__ b,
                                              u16* __restrict__ out) {
  int t = threadIdx.x;
  int n = blockIdx.x * 4 + (t >> 6);
  int l = t & 63;
  int g = (l >> 3), sub = l & 7;
  float4 acc = agg_row_wide(hs, row_ptr, col, n, g, sub);
  if (g == 0) {
    float d = dis[n];
    float4 bq = ((const float4*)b)[sub];
    float4 o;
    o.x = fmaxf(fmaf(acc.x, d, bq.x), 0.f);
    o.y = fmaxf(fmaf(acc.y, d, bq.y), 0.f);
    o.z = fmaxf(fmaf(acc.z, d, bq.z), 0.f);
    o.w = fmaxf(fmaf(acc.w, d, bq.w), 0.f);
    ((u16x4*)(out + (size_t)n * EMB))[sub] = f4_to_h4(o);
  }
}

// pooling tail: privatized 64-copy accumulator kills same-line atomic contention
__global__ __launch_bounds__(256) void k_agg2pool(const u16* __restrict__ hs,
                                                  const int* __restrict__ row_ptr,
                                                  const int* __restrict__ col,
                                                  const float* __restrict__ dis,
                                                  const float* __restrict__ b2,
                                                  const float* __restrict__ Wo,
                                                  const int* __restrict__ batch,
                                                  float* __restrict__ gaccP) {
  int t = threadIdx.x;
  int n = blockIdx.x * 4 + (t >> 6);
  int l = t & 63;
  int g = (l >> 3), sub = l & 7;
  float4 acc = agg_row_wide(hs, row_ptr, col, n, g, sub);
  float d = dis[n];
  float4 bq = ((const float4*)b2)[sub];
  float4 wq = ((const float4*)Wo)[sub];
  float p = fmaxf(fmaf(acc.x, d, bq.x), 0.f) * wq.x
          + fmaxf(fmaf(acc.y, d, bq.y), 0.f) * wq.y
          + fmaxf(fmaf(acc.z, d, bq.z), 0.f) * wq.z
          + fmaxf(fmaf(acc.w, d, bq.w), 0.f) * wq.w;
  p += __shfl_xor(p, 1);
  p += __shfl_xor(p, 2);
  p += __shfl_xor(p, 4);
  if (l == 0) {
    int copy = blockIdx.x & (NCOPY - 1);   // consecutive blocks -> different copies
    atomicAdd(&gaccP[copy * N_GRAPHS + batch[n]], p);
  }
}

__global__ __launch_bounds__(256) void k_finalize(const float* __restrict__ gaccP,
                                                  const int* __restrict__ gcnt,
                                                  const float* __restrict__ bo,
                                                  float* __restrict__ out) {
  int g = blockIdx.x * 256 + threadIdx.x;
  if (g < N_GRAPHS) {
    float s = 0.f;
#pragma unroll 8
    for (int c = 0; c < NCOPY; ++c) s += gaccP[c * N_GRAPHS + g];
    out[g] = s / fmaxf((float)gcnt[g], 1.0f) + bo[0];
  }
}

// ---------------- launch ----------------

extern "C" void kernel_launch(void* const* d_in, const int* in_sizes, int n_in,
                              void* d_out, int out_size, void* d_ws, size_t ws_size,
                              hipStream_t stream) {
  const float* x     = (const float*)d_in[0];
  const int*   ei    = (const int*)d_in[1];   // [2, E]: src then dst
  const int*   batch = (const int*)d_in[2];
  const float* W1    = (const float*)d_in[3];
  const float* b1    = (const float*)d_in[4];
  const float* W2    = (const float*)d_in[5];
  const float* b2    = (const float*)d_in[6];
  const float* Wo    = (const float*)d_in[7];
  const float* bo    = (const float*)d_in[8];
  float* out = (float*)d_out;

  const int* src = ei;
  const int* dst = ei + N_EDGES;

  char* w = (char*)d_ws;
  int*   degcnt  = (int*)w;    w += (size_t)N_NODES * 4;            // zeroed
  int*   cursor  = (int*)w;    w += (size_t)N_NODES * 4;            // zeroed
  float* gaccP   = (float*)w;  w += (size_t)NCOPY * N_GRAPHS * 4;   // zeroed
  size_t zero_bytes = (size_t)(w - (char*)d_ws);
  int*   gcnt    = (int*)w;    w += (size_t)N_GRAPHS * 4;           // written by k_gcnt
  int*   row_ptr = (int*)w;    w += (size_t)(N_NODES + 4) * 4;
  int*   blocksum= (int*)w;    w += 128 * 4;
  int*   blockoff= (int*)w;    w += 128 * 4;
  int*   col     = (int*)w;    w += (size_t)PADCAP * 4;
  float* dis     = (float*)w;  w += (size_t)N_NODES * 4;
  u16*   hs1     = (u16*)w;    w += (size_t)(N_NODES + 1) * EMB * 2;  // +1 zero row
  u16*   out1    = (u16*)w;    w += (size_t)N_NODES * EMB * 2;
  u16*   hs2     = hs1;  // hs1 dead after agg1; zero row persists

  const int EB = (N_EDGES + 255) / 256;    // 6250
  const int NB = (N_NODES + 255) / 256;    // 391
  const int SB = (N_NODES + 1023) / 1024;  // 98
  const int RB = N_NODES / 8;              // 12500 (exact)
  const int AB = N_NODES / 4;              // 25000 wave-per-node blocks
  const int CB = (PADCAP + 255) / 256;

  (void)hipMemsetAsync(d_ws, 0, zero_bytes, stream);

  k_hist<<<EB, 256, 0, stream>>>(dst, degcnt);
  k_node_init<<<NB, 256, 0, stream>>>(degcnt, dis);
  k_gcnt<<<1, 512, 0, stream>>>(batch, gcnt);
  k_colfill<<<CB, 256, 0, stream>>>(col, hs1);
  k_scanA<<<SB, 256, 0, stream>>>(degcnt, blocksum);
  k_scanB<<<1, 128, 0, stream>>>(blocksum, blockoff, row_ptr + N_NODES, SB);
  k_scanC<<<SB, 256, 0, stream>>>(degcnt, blockoff, row_ptr);
  k_fillg<<<2048, 256, 0, stream>>>(src, dst, row_ptr, cursor, col);

  k_gemm1<<<RB, 256, 0, stream>>>(x, W1, dis, hs1);
  k_agg1<<<AB, 256, 0, stream>>>(hs1, row_ptr, col, dis, b1, out1);
  k_gemm2<<<RB, 256, 0, stream>>>(out1, W2, dis, hs2);
  k_agg2pool<<<AB, 256, 0, stream>>>(hs2, row_ptr, col, dis, b2, Wo, batch, gaccP);
  k_finalize<<<2, 256, 0, stream>>>(gaccP, gcnt, bo, out);
}

// Round 9
// 416.221 us; speedup vs baseline: 2.0235x; 1.0445x over previous
//
#include <hip/hip_runtime.h>
#include <hip/hip_fp16.h>

#define N_NODES 100000
#define N_EDGES 1600000
#define N_GRAPHS 512
#define FEAT 128
#define EMB 32
#define ZROW N_NODES                        // dedicated zero row for padding
#define PADCAP (N_EDGES + 8 * N_NODES)      // pad8 worst-case col slots
#define NCOPY 64                            // privatized pool accumulator copies
#define NBKT 250                            // dst buckets (400 nodes each)
#define NPB 400                             // nodes per bucket
#define ABLK 128                            // bin phase blocks
#define EPB (N_EDGES / ABLK)                // 12500 edges per bin block

typedef unsigned short u16;
typedef unsigned int u32;
typedef float f32x4 __attribute__((ext_vector_type(4)));
typedef unsigned short u16x4 __attribute__((ext_vector_type(4)));

__device__ __forceinline__ int pad8(int d) { return (d + 7) & ~7; }

__device__ __forceinline__ float4 h4_to_f4(u16x4 v) {
  union { unsigned int u; __half2 h; } a, b;
  a.u = (unsigned int)v.x | ((unsigned int)v.y << 16);
  b.u = (unsigned int)v.z | ((unsigned int)v.w << 16);
  float2 f0 = __half22float2(a.h);
  float2 f1 = __half22float2(b.h);
  return make_float4(f0.x, f0.y, f1.x, f1.y);
}

__device__ __forceinline__ u16x4 f4_to_h4(float4 f) {
  union { unsigned int u; __half2 h; } a, b;
  a.h = __float22half2_rn(make_float2(f.x, f.y));
  b.h = __float22half2_rn(make_float2(f.z, f.w));
  u16x4 r;
  r.x = (u16)(a.u & 0xffff); r.y = (u16)(a.u >> 16);
  r.z = (u16)(b.u & 0xffff); r.w = (u16)(b.u >> 16);
  return r;
}

// ---------------- degree / misc ----------------

__global__ __launch_bounds__(256) void k_hist(const int* __restrict__ dst,
                                              int* __restrict__ degcnt) {
  int e = blockIdx.x * 256 + threadIdx.x;
  if (e < N_EDGES) atomicAdd(&degcnt[dst[e]], 1);
}

// pure elementwise; also zero the fp16 zero-row of hs1
__global__ __launch_bounds__(256) void k_node_init(const int* __restrict__ degcnt,
                                                   float* __restrict__ dis,
                                                   u16* __restrict__ hs1) {
  int i = blockIdx.x * 256 + threadIdx.x;
  if (i < N_NODES) dis[i] = rsqrtf((float)degcnt[i] + 1.0f);
  if (i < EMB) hs1[(size_t)ZROW * EMB + i] = 0;
}

// batch is sorted: per-graph counts via binary search, zero atomics
__global__ __launch_bounds__(512) void k_gcnt(const int* __restrict__ batch,
                                              int* __restrict__ gcnt) {
  __shared__ int first[N_GRAPHS + 1];
  int g = threadIdx.x;
  int lo = 0, hi = N_NODES;
  while (lo < hi) {
    int mid = (lo + hi) >> 1;
    if (batch[mid] < g) lo = mid + 1; else hi = mid;
  }
  first[g] = lo;
  if (g == 0) first[N_GRAPHS] = N_NODES;
  __syncthreads();
  gcnt[g] = first[g + 1] - first[g];
}

// ---------------- row_ptr scans (over pad8(deg)) ----------------

__global__ __launch_bounds__(256) void k_scanA(const int* __restrict__ degcnt,
                                               int* __restrict__ blocksum) {
  __shared__ int sh[256];
  int t = threadIdx.x;
  int base = blockIdx.x * 1024;
  int s = 0;
#pragma unroll
  for (int j = 0; j < 4; j++) {
    int idx = base + t * 4 + j;
    if (idx < N_NODES) s += pad8(degcnt[idx]);
  }
  sh[t] = s;
  __syncthreads();
  for (int off = 128; off > 0; off >>= 1) {
    if (t < off) sh[t] += sh[t + off];
    __syncthreads();
  }
  if (t == 0) blocksum[blockIdx.x] = sh[0];
}

__global__ __launch_bounds__(128) void k_scanB(const int* __restrict__ blocksum,
                                               int* __restrict__ blockoff,
                                               int* __restrict__ total_out, int nb) {
  __shared__ int sh[128];
  int t = threadIdx.x;
  int v = (t < nb) ? blocksum[t] : 0;
  sh[t] = v;
  __syncthreads();
  for (int off = 1; off < 128; off <<= 1) {
    int add = (t >= off) ? sh[t - off] : 0;
    __syncthreads();
    sh[t] += add;
    __syncthreads();
  }
  if (t < nb) blockoff[t] = sh[t] - v;   // exclusive
  if (t == nb - 1) total_out[0] = sh[t];
}

__global__ __launch_bounds__(256) void k_scanC(const int* __restrict__ degcnt,
                                               const int* __restrict__ blockoff,
                                               int* __restrict__ row_ptr) {
  __shared__ int sh[256];
  int t = threadIdx.x;
  int base = blockIdx.x * 1024;
  int v[4];
#pragma unroll
  for (int j = 0; j < 4; j++) {
    int idx = base + t * 4 + j;
    v[j] = (idx < N_NODES) ? pad8(degcnt[idx]) : 0;
  }
  int tsum = v[0] + v[1] + v[2] + v[3];
  sh[t] = tsum;
  __syncthreads();
  for (int off = 1; off < 256; off <<= 1) {
    int add = (t >= off) ? sh[t - off] : 0;
    __syncthreads();
    sh[t] += add;
    __syncthreads();
  }
  int p = sh[t] - tsum + blockoff[blockIdx.x];
#pragma unroll
  for (int j = 0; j < 4; j++) {
    int idx = base + t * 4 + j;
    if (idx < N_NODES) row_ptr[idx] = p;
    p += v[j];
  }
}

// ---------------- two-phase binned CSR fill ----------------

// A1: per-block LDS histogram over 250 dst buckets
__global__ __launch_bounds__(256) void k_binA(const int* __restrict__ dst,
                                              int* __restrict__ cnt) {
  __shared__ int h[NBKT];
  int k = blockIdx.x, t = threadIdx.x;
  for (int i = t; i < NBKT; i += 256) h[i] = 0;
  __syncthreads();
  int e0 = k * EPB;
  for (int e = e0 + t; e < e0 + EPB; e += 256)
    atomicAdd(&h[(u32)dst[e] / (u32)NPB], 1);
  __syncthreads();
  for (int i = t; i < NBKT; i += 256) cnt[k * NBKT + i] = h[i];
}

// A2a: per bucket, exclusive scan over the 128 block counts
__global__ __launch_bounds__(128) void k_binscanA(const int* __restrict__ cnt,
                                                  int* __restrict__ off,
                                                  int* __restrict__ tot) {
  __shared__ int sh[128];
  int b = blockIdx.x, t = threadIdx.x;
  int v = cnt[t * NBKT + b];
  sh[t] = v;
  __syncthreads();
  for (int o = 1; o < 128; o <<= 1) {
    int add = (t >= o) ? sh[t - o] : 0;
    __syncthreads();
    sh[t] += add;
    __syncthreads();
  }
  off[t * NBKT + b] = sh[t] - v;
  if (t == 127) tot[b] = sh[127];
}

// A2b: exclusive scan of the 250 bucket totals -> bucketBase[251]
__global__ __launch_bounds__(256) void k_binscanB(const int* __restrict__ tot,
                                                  int* __restrict__ base) {
  __shared__ int sh[256];
  int t = threadIdx.x;
  int v = (t < NBKT) ? tot[t] : 0;
  sh[t] = v;
  __syncthreads();
  for (int o = 1; o < 256; o <<= 1) {
    int add = (t >= o) ? sh[t - o] : 0;
    __syncthreads();
    sh[t] += add;
    __syncthreads();
  }
  if (t < NBKT) base[t] = sh[t] - v;
  if (t == NBKT - 1) base[NBKT] = sh[t];
}

// A3: scatter packed (src*400 + local_dst) into dense binbuf; per-(block,bucket)
// runs are contiguous (~50 words) and short-lived -> minimal write amplification
__global__ __launch_bounds__(256) void k_binscat(const int* __restrict__ src,
                                                 const int* __restrict__ dst,
                                                 const int* __restrict__ off,
                                                 const int* __restrict__ base,
                                                 u32* __restrict__ binbuf) {
  __shared__ int posB[NBKT];
  __shared__ int h[NBKT];
  int k = blockIdx.x, t = threadIdx.x;
  for (int i = t; i < NBKT; i += 256) {
    posB[i] = base[i] + off[k * NBKT + i];
    h[i] = 0;
  }
  __syncthreads();
  int e0 = k * EPB;
  for (int e = e0 + t; e < e0 + EPB; e += 256) {
    u32 d = (u32)dst[e];
    int b = d / (u32)NPB;
    int r = atomicAdd(&h[b], 1);
    binbuf[posB[b] + r] = (u32)src[e] * (u32)NPB + (d - (u32)b * NPB);
  }
}

// B: one block per bucket; LDS cursors; private ~32KB col window (single
// writer block, short lifetime -> lines merge in its XCD L2). Also writes
// the ZROW pad slots (replaces k_colfill).
__global__ __launch_bounds__(256) void k_fillB(const u32* __restrict__ binbuf,
                                               const int* __restrict__ base,
                                               const int* __restrict__ row_ptr,
                                               int* __restrict__ col) {
  __shared__ int rp[NPB + 1];
  __shared__ int cur[NPB];
  int b = blockIdx.x, t = threadIdx.x;
  for (int i = t; i < NPB + 1; i += 256) rp[i] = row_ptr[b * NPB + i];
  for (int i = t; i < NPB; i += 256) cur[i] = 0;
  __syncthreads();
  int s0 = base[b], s1 = base[b + 1];
  for (int i = s0 + t; i < s1; i += 256) {
    u32 p = binbuf[i];
    u32 s = p / (u32)NPB;
    int ld = p - s * (u32)NPB;
    int pos = atomicAdd(&cur[ld], 1);
    col[rp[ld] + pos] = (int)s;
  }
  __syncthreads();
  for (int ld = t; ld < NPB; ld += 256) {
    int bs = rp[ld], len = rp[ld + 1] - bs, c = cur[ld];
    for (int j = c; j < len; j++) col[bs + j] = ZROW;
  }
}

// ---------------- GEMMs (pre-scaled by deg_inv_sqrt, fp16 output) ----------------

__global__ __launch_bounds__(256) void k_gemm1(const float* __restrict__ x,
                                               const float* __restrict__ W1,
                                               const float* __restrict__ dis,
                                               u16* __restrict__ hs1) {
  __shared__ float Wl[FEAT * EMB];  // 16 KB
  int t = threadIdx.x;
  for (int i = t; i < FEAT * EMB; i += 256) Wl[i] = W1[i];
  __syncthreads();
  int row = blockIdx.x * 8 + (t >> 5);
  int c = t & 31;
  const f32x4* xr = (const f32x4*)(x + (size_t)row * FEAT);
  float acc = 0.f;
#pragma unroll
  for (int k4 = 0; k4 < FEAT / 4; ++k4) {
    f32x4 xv = __builtin_nontemporal_load(&xr[k4]);  // one-touch stream
    acc = fmaf(xv.x, Wl[(k4 * 4 + 0) * EMB + c], acc);
    acc = fmaf(xv.y, Wl[(k4 * 4 + 1) * EMB + c], acc);
    acc = fmaf(xv.z, Wl[(k4 * 4 + 2) * EMB + c], acc);
    acc = fmaf(xv.w, Wl[(k4 * 4 + 3) * EMB + c], acc);
  }
  hs1[row * EMB + c] = __half_as_ushort(__float2half_rn(acc * dis[row]));
}

__global__ __launch_bounds__(256) void k_gemm2(const u16* __restrict__ in1,
                                               const float* __restrict__ W2,
                                               const float* __restrict__ dis,
                                               u16* __restrict__ hs2) {
  __shared__ float Wl[EMB * EMB];  // 4 KB
  int t = threadIdx.x;
  for (int i = t; i < EMB * EMB; i += 256) Wl[i] = W2[i];
  __syncthreads();
  int row = blockIdx.x * 8 + (t >> 5);
  int c = t & 31;
  const u16x4* xr = (const u16x4*)(in1 + (size_t)row * EMB);
  float acc = 0.f;
#pragma unroll
  for (int q = 0; q < 8; ++q) {
    float4 xv = h4_to_f4(xr[q]);
    acc = fmaf(xv.x, Wl[(q * 4 + 0) * EMB + c], acc);
    acc = fmaf(xv.y, Wl[(q * 4 + 1) * EMB + c], acc);
    acc = fmaf(xv.z, Wl[(q * 4 + 2) * EMB + c], acc);
    acc = fmaf(xv.w, Wl[(q * 4 + 3) * EMB + c], acc);
  }
  hs2[row * EMB + c] = __half_as_ushort(__float2half_rn(acc * dis[row]));
}

// ---------------- Aggregation: wave-per-node, 8 rows per gather instruction ----------------

__device__ __forceinline__ float4 agg_row_wide(const u16* __restrict__ hs,
                                               const int* __restrict__ row_ptr,
                                               const int* __restrict__ col,
                                               int n, int g, int sub) {
  const u16x4* hs4 = (const u16x4*)hs;
  int e0 = row_ptr[n], e1 = row_ptr[n + 1];   // multiple of 8 apart
  int nch = (e1 - e0) >> 3;
  int ec = e0 + g;
  float4 acc = make_float4(0.f, 0.f, 0.f, 0.f);
  int s0 = (nch > 0) ? __builtin_nontemporal_load(&col[ec]) : ZROW;
  int s1 = (nch > 1) ? __builtin_nontemporal_load(&col[ec + 8]) : ZROW;
  int i = 0;
  for (; i + 2 <= nch; i += 2) {
    u16x4 va = hs4[(size_t)s0 * 8 + sub];
    u16x4 vb = hs4[(size_t)s1 * 8 + sub];
    int t0 = (i + 2 < nch) ? __builtin_nontemporal_load(&col[ec + (i + 2) * 8]) : ZROW;
    int t1 = (i + 3 < nch) ? __builtin_nontemporal_load(&col[ec + (i + 3) * 8]) : ZROW;
    float4 fa = h4_to_f4(va);
    float4 fb = h4_to_f4(vb);
    acc.x += fa.x + fb.x;
    acc.y += fa.y + fb.y;
    acc.z += fa.z + fb.z;
    acc.w += fa.w + fb.w;
    s0 = t0;
    s1 = t1;
  }
  if (i < nch) {
    float4 fa = h4_to_f4(hs4[(size_t)s0 * 8 + sub]);
    acc.x += fa.x; acc.y += fa.y; acc.z += fa.z; acc.w += fa.w;
  }
#pragma unroll
  for (int m = 8; m < 64; m <<= 1) {
    acc.x += __shfl_xor(acc.x, m);
    acc.y += __shfl_xor(acc.y, m);
    acc.z += __shfl_xor(acc.z, m);
    acc.w += __shfl_xor(acc.w, m);
  }
  // self-loop (hs already dis-scaled); added post-reduction => counted once
  float4 sf = h4_to_f4(hs4[(size_t)n * 8 + sub]);
  acc.x += sf.x; acc.y += sf.y; acc.z += sf.z; acc.w += sf.w;
  return acc;
}

__global__ __launch_bounds__(256) void k_agg1(const u16* __restrict__ hs,
                                              const int* __restrict__ row_ptr,
                                              const int* __restrict__ col,
                                              const float* __restrict__ dis,
                                              const float* __restrict__ b,
                                              u16* __restrict__ out) {
  int t = threadIdx.x;
  int n = blockIdx.x * 4 + (t >> 6);
  int l = t & 63;
  int g = (l >> 3), sub = l & 7;
  float4 acc = agg_row_wide(hs, row_ptr, col, n, g, sub);
  if (g == 0) {
    float d = dis[n];
    float4 bq = ((const float4*)b)[sub];
    float4 o;
    o.x = fmaxf(fmaf(acc.x, d, bq.x), 0.f);
    o.y = fmaxf(fmaf(acc.y, d, bq.y), 0.f);
    o.z = fmaxf(fmaf(acc.z, d, bq.z), 0.f);
    o.w = fmaxf(fmaf(acc.w, d, bq.w), 0.f);
    ((u16x4*)(out + (size_t)n * EMB))[sub] = f4_to_h4(o);
  }
}

// pooling tail: privatized 64-copy accumulator kills same-line atomic contention
__global__ __launch_bounds__(256) void k_agg2pool(const u16* __restrict__ hs,
                                                  const int* __restrict__ row_ptr,
                                                  const int* __restrict__ col,
                                                  const float* __restrict__ dis,
                                                  const float* __restrict__ b2,
                                                  const float* __restrict__ Wo,
                                                  const int* __restrict__ batch,
                                                  float* __restrict__ gaccP) {
  int t = threadIdx.x;
  int n = blockIdx.x * 4 + (t >> 6);
  int l = t & 63;
  int g = (l >> 3), sub = l & 7;
  float4 acc = agg_row_wide(hs, row_ptr, col, n, g, sub);
  float d = dis[n];
  float4 bq = ((const float4*)b2)[sub];
  float4 wq = ((const float4*)Wo)[sub];
  float p = fmaxf(fmaf(acc.x, d, bq.x), 0.f) * wq.x
          + fmaxf(fmaf(acc.y, d, bq.y), 0.f) * wq.y
          + fmaxf(fmaf(acc.z, d, bq.z), 0.f) * wq.z
          + fmaxf(fmaf(acc.w, d, bq.w), 0.f) * wq.w;
  p += __shfl_xor(p, 1);
  p += __shfl_xor(p, 2);
  p += __shfl_xor(p, 4);
  if (l == 0) {
    int copy = blockIdx.x & (NCOPY - 1);   // consecutive blocks -> different copies
    atomicAdd(&gaccP[copy * N_GRAPHS + batch[n]], p);
  }
}

__global__ __launch_bounds__(256) void k_finalize(const float* __restrict__ gaccP,
                                                  const int* __restrict__ gcnt,
                                                  const float* __restrict__ bo,
                                                  float* __restrict__ out) {
  int g = blockIdx.x * 256 + threadIdx.x;
  if (g < N_GRAPHS) {
    float s = 0.f;
#pragma unroll 8
    for (int c = 0; c < NCOPY; ++c) s += gaccP[c * N_GRAPHS + g];
    out[g] = s / fmaxf((float)gcnt[g], 1.0f) + bo[0];
  }
}

// ---------------- launch ----------------

extern "C" void kernel_launch(void* const* d_in, const int* in_sizes, int n_in,
                              void* d_out, int out_size, void* d_ws, size_t ws_size,
                              hipStream_t stream) {
  const float* x     = (const float*)d_in[0];
  const int*   ei    = (const int*)d_in[1];   // [2, E]: src then dst
  const int*   batch = (const int*)d_in[2];
  const float* W1    = (const float*)d_in[3];
  const float* b1    = (const float*)d_in[4];
  const float* W2    = (const float*)d_in[5];
  const float* b2    = (const float*)d_in[6];
  const float* Wo    = (const float*)d_in[7];
  const float* bo    = (const float*)d_in[8];
  float* out = (float*)d_out;

  const int* src = ei;
  const int* dst = ei + N_EDGES;

  char* w = (char*)d_ws;
  int*   degcnt  = (int*)w;    w += (size_t)N_NODES * 4;            // zeroed
  float* gaccP   = (float*)w;  w += (size_t)NCOPY * N_GRAPHS * 4;   // zeroed
  size_t zero_bytes = (size_t)(w - (char*)d_ws);
  int*   gcnt    = (int*)w;    w += (size_t)N_GRAPHS * 4;
  int*   row_ptr = (int*)w;    w += (size_t)(N_NODES + 4) * 4;
  int*   blocksum= (int*)w;    w += 128 * 4;
  int*   blockoff= (int*)w;    w += 128 * 4;
  int*   cnt     = (int*)w;    w += (size_t)ABLK * NBKT * 4;
  int*   boff    = (int*)w;    w += (size_t)ABLK * NBKT * 4;
  int*   btot    = (int*)w;    w += (size_t)(NBKT + 8) * 4;
  int*   bbase   = (int*)w;    w += (size_t)(NBKT + 8) * 4;
  int*   col     = (int*)w;    w += (size_t)PADCAP * 4;
  float* dis     = (float*)w;  w += (size_t)N_NODES * 4;
  u16*   hs1     = (u16*)w;    w += (size_t)(N_NODES + 1) * EMB * 2;  // +1 zero row
  u16*   out1    = (u16*)w;    w += (size_t)N_NODES * EMB * 2;        // 6.4 MB
  u32*   binbuf  = (u32*)out1;  // alias: binbuf (6.4 MB) dead before agg1 writes out1
  u16*   hs2     = hs1;         // hs1 dead after agg1; zero row persists

  const int EB = (N_EDGES + 255) / 256;    // 6250
  const int NB = (N_NODES + 255) / 256;    // 391
  const int SB = (N_NODES + 1023) / 1024;  // 98
  const int RB = N_NODES / 8;              // 12500 (exact)
  const int AB = N_NODES / 4;              // 25000 wave-per-node blocks

  (void)hipMemsetAsync(d_ws, 0, zero_bytes, stream);

  k_hist<<<EB, 256, 0, stream>>>(dst, degcnt);
  k_node_init<<<NB, 256, 0, stream>>>(degcnt, dis, hs1);
  k_gcnt<<<1, 512, 0, stream>>>(batch, gcnt);
  k_scanA<<<SB, 256, 0, stream>>>(degcnt, blocksum);
  k_scanB<<<1, 128, 0, stream>>>(blocksum, blockoff, row_ptr + N_NODES, SB);
  k_scanC<<<SB, 256, 0, stream>>>(degcnt, blockoff, row_ptr);

  k_binA<<<ABLK, 256, 0, stream>>>(dst, cnt);
  k_binscanA<<<NBKT, 128, 0, stream>>>(cnt, boff, btot);
  k_binscanB<<<1, 256, 0, stream>>>(btot, bbase);
  k_binscat<<<ABLK, 256, 0, stream>>>(src, dst, boff, bbase, binbuf);
  k_fillB<<<NBKT, 256, 0, stream>>>(binbuf, bbase, row_ptr, col);

  k_gemm1<<<RB, 256, 0, stream>>>(x, W1, dis, hs1);
  k_agg1<<<AB, 256, 0, stream>>>(hs1, row_ptr, col, dis, b1, out1);
  k_gemm2<<<RB, 256, 0, stream>>>(out1, W2, dis, hs2);
  k_agg2pool<<<AB, 256, 0, stream>>>(hs2, row_ptr, col, dis, b2, Wo, batch, gaccP);
  k_finalize<<<2, 256, 0, stream>>>(gaccP, gcnt, bo, out);
}

// Round 10
// 359.108 us; speedup vs baseline: 2.3454x; 1.1590x over previous
//
#include <hip/hip_runtime.h>
#include <hip/hip_fp16.h>

#define N_NODES 100000
#define N_EDGES 1600000
#define N_GRAPHS 512
#define FEAT 128
#define EMB 32
#define ZROW N_NODES                        // dedicated zero row for padding
#define PADCAP (N_EDGES + 8 * N_NODES)      // pad8 worst-case col slots
#define NCOPY 64                            // privatized pool accumulator copies
#define NBKT 250                            // dst buckets (400 nodes each)
#define NPB 400                             // nodes per bucket
#define ABLK 128                            // bin phase blocks
#define EPB (N_EDGES / ABLK)                // 12500 edges per bin block
#define NTILE (N_NODES / 16)                // 6250 MFMA row tiles

typedef unsigned short u16;
typedef unsigned int u32;
typedef _Float16 f16;
typedef float f32x4 __attribute__((ext_vector_type(4)));
typedef unsigned short u16x4 __attribute__((ext_vector_type(4)));
typedef f16 f16x8 __attribute__((ext_vector_type(8)));

__device__ __forceinline__ int pad8(int d) { return (d + 7) & ~7; }

__device__ __forceinline__ float4 h4_to_f4(u16x4 v) {
  union { unsigned int u; __half2 h; } a, b;
  a.u = (unsigned int)v.x | ((unsigned int)v.y << 16);
  b.u = (unsigned int)v.z | ((unsigned int)v.w << 16);
  float2 f0 = __half22float2(a.h);
  float2 f1 = __half22float2(b.h);
  return make_float4(f0.x, f0.y, f1.x, f1.y);
}

__device__ __forceinline__ u16x4 f4_to_h4(float4 f) {
  union { unsigned int u; __half2 h; } a, b;
  a.h = __float22half2_rn(make_float2(f.x, f.y));
  b.h = __float22half2_rn(make_float2(f.z, f.w));
  u16x4 r;
  r.x = (u16)(a.u & 0xffff); r.y = (u16)(a.u >> 16);
  r.z = (u16)(b.u & 0xffff); r.w = (u16)(b.u >> 16);
  return r;
}

// ---------------- degree / misc ----------------

__global__ __launch_bounds__(256) void k_hist(const int* __restrict__ dst,
                                              int* __restrict__ degcnt) {
  int e = blockIdx.x * 256 + threadIdx.x;
  if (e < N_EDGES) atomicAdd(&degcnt[dst[e]], 1);
}

// pure elementwise; also zero the fp16 zero-row of hs1
__global__ __launch_bounds__(256) void k_node_init(const int* __restrict__ degcnt,
                                                   float* __restrict__ dis,
                                                   u16* __restrict__ hs1) {
  int i = blockIdx.x * 256 + threadIdx.x;
  if (i < N_NODES) dis[i] = rsqrtf((float)degcnt[i] + 1.0f);
  if (i < EMB) hs1[(size_t)ZROW * EMB + i] = 0;
}

// batch is sorted: per-graph counts via binary search, zero atomics
__global__ __launch_bounds__(512) void k_gcnt(const int* __restrict__ batch,
                                              int* __restrict__ gcnt) {
  __shared__ int first[N_GRAPHS + 1];
  int g = threadIdx.x;
  int lo = 0, hi = N_NODES;
  while (lo < hi) {
    int mid = (lo + hi) >> 1;
    if (batch[mid] < g) lo = mid + 1; else hi = mid;
  }
  first[g] = lo;
  if (g == 0) first[N_GRAPHS] = N_NODES;
  __syncthreads();
  gcnt[g] = first[g + 1] - first[g];
}

// ---------------- row_ptr scans (over pad8(deg)) ----------------

__global__ __launch_bounds__(256) void k_scanA(const int* __restrict__ degcnt,
                                               int* __restrict__ blocksum) {
  __shared__ int sh[256];
  int t = threadIdx.x;
  int base = blockIdx.x * 1024;
  int s = 0;
#pragma unroll
  for (int j = 0; j < 4; j++) {
    int idx = base + t * 4 + j;
    if (idx < N_NODES) s += pad8(degcnt[idx]);
  }
  sh[t] = s;
  __syncthreads();
  for (int off = 128; off > 0; off >>= 1) {
    if (t < off) sh[t] += sh[t + off];
    __syncthreads();
  }
  if (t == 0) blocksum[blockIdx.x] = sh[0];
}

__global__ __launch_bounds__(128) void k_scanB(const int* __restrict__ blocksum,
                                               int* __restrict__ blockoff,
                                               int* __restrict__ total_out, int nb) {
  __shared__ int sh[128];
  int t = threadIdx.x;
  int v = (t < nb) ? blocksum[t] : 0;
  sh[t] = v;
  __syncthreads();
  for (int off = 1; off < 128; off <<= 1) {
    int add = (t >= off) ? sh[t - off] : 0;
    __syncthreads();
    sh[t] += add;
    __syncthreads();
  }
  if (t < nb) blockoff[t] = sh[t] - v;   // exclusive
  if (t == nb - 1) total_out[0] = sh[t];
}

__global__ __launch_bounds__(256) void k_scanC(const int* __restrict__ degcnt,
                                               const int* __restrict__ blockoff,
                                               int* __restrict__ row_ptr) {
  __shared__ int sh[256];
  int t = threadIdx.x;
  int base = blockIdx.x * 1024;
  int v[4];
#pragma unroll
  for (int j = 0; j < 4; j++) {
    int idx = base + t * 4 + j;
    v[j] = (idx < N_NODES) ? pad8(degcnt[idx]) : 0;
  }
  int tsum = v[0] + v[1] + v[2] + v[3];
  sh[t] = tsum;
  __syncthreads();
  for (int off = 1; off < 256; off <<= 1) {
    int add = (t >= off) ? sh[t - off] : 0;
    __syncthreads();
    sh[t] += add;
    __syncthreads();
  }
  int p = sh[t] - tsum + blockoff[blockIdx.x];
#pragma unroll
  for (int j = 0; j < 4; j++) {
    int idx = base + t * 4 + j;
    if (idx < N_NODES) row_ptr[idx] = p;
    p += v[j];
  }
}

// ---------------- two-phase binned CSR fill ----------------

__global__ __launch_bounds__(256) void k_binA(const int* __restrict__ dst,
                                              int* __restrict__ cnt) {
  __shared__ int h[NBKT];
  int k = blockIdx.x, t = threadIdx.x;
  for (int i = t; i < NBKT; i += 256) h[i] = 0;
  __syncthreads();
  int e0 = k * EPB;
  for (int e = e0 + t; e < e0 + EPB; e += 256)
    atomicAdd(&h[(u32)dst[e] / (u32)NPB], 1);
  __syncthreads();
  for (int i = t; i < NBKT; i += 256) cnt[k * NBKT + i] = h[i];
}

__global__ __launch_bounds__(128) void k_binscanA(const int* __restrict__ cnt,
                                                  int* __restrict__ off,
                                                  int* __restrict__ tot) {
  __shared__ int sh[128];
  int b = blockIdx.x, t = threadIdx.x;
  int v = cnt[t * NBKT + b];
  sh[t] = v;
  __syncthreads();
  for (int o = 1; o < 128; o <<= 1) {
    int add = (t >= o) ? sh[t - o] : 0;
    __syncthreads();
    sh[t] += add;
    __syncthreads();
  }
  off[t * NBKT + b] = sh[t] - v;
  if (t == 127) tot[b] = sh[127];
}

__global__ __launch_bounds__(256) void k_binscanB(const int* __restrict__ tot,
                                                  int* __restrict__ base) {
  __shared__ int sh[256];
  int t = threadIdx.x;
  int v = (t < NBKT) ? tot[t] : 0;
  sh[t] = v;
  __syncthreads();
  for (int o = 1; o < 256; o <<= 1) {
    int add = (t >= o) ? sh[t - o] : 0;
    __syncthreads();
    sh[t] += add;
    __syncthreads();
  }
  if (t < NBKT) base[t] = sh[t] - v;
  if (t == NBKT - 1) base[NBKT] = sh[t];
}

__global__ __launch_bounds__(256) void k_binscat(const int* __restrict__ src,
                                                 const int* __restrict__ dst,
                                                 const int* __restrict__ off,
                                                 const int* __restrict__ base,
                                                 u32* __restrict__ binbuf) {
  __shared__ int posB[NBKT];
  __shared__ int h[NBKT];
  int k = blockIdx.x, t = threadIdx.x;
  for (int i = t; i < NBKT; i += 256) {
    posB[i] = base[i] + off[k * NBKT + i];
    h[i] = 0;
  }
  __syncthreads();
  int e0 = k * EPB;
  for (int e = e0 + t; e < e0 + EPB; e += 256) {
    u32 d = (u32)dst[e];
    int b = d / (u32)NPB;
    int r = atomicAdd(&h[b], 1);
    binbuf[posB[b] + r] = (u32)src[e] * (u32)NPB + (d - (u32)b * NPB);
  }
}

__global__ __launch_bounds__(256) void k_fillB(const u32* __restrict__ binbuf,
                                               const int* __restrict__ base,
                                               const int* __restrict__ row_ptr,
                                               int* __restrict__ col) {
  __shared__ int rp[NPB + 1];
  __shared__ int cur[NPB];
  int b = blockIdx.x, t = threadIdx.x;
  for (int i = t; i < NPB + 1; i += 256) rp[i] = row_ptr[b * NPB + i];
  for (int i = t; i < NPB; i += 256) cur[i] = 0;
  __syncthreads();
  int s0 = base[b], s1 = base[b + 1];
  for (int i = s0 + t; i < s1; i += 256) {
    u32 p = binbuf[i];
    u32 s = p / (u32)NPB;
    int ld = p - s * (u32)NPB;
    int pos = atomicAdd(&cur[ld], 1);
    col[rp[ld] + pos] = (int)s;
  }
  __syncthreads();
  for (int ld = t; ld < NPB; ld += 256) {
    int bs = rp[ld], len = rp[ld + 1] - bs, c = cur[ld];
    for (int j = c; j < len; j++) col[bs + j] = ZROW;
  }
}

// ---------------- GEMMs via MFMA 16x16x32 f16 (W in register B-frags) ----------------
// A layout: lane l holds A[m = l&15][k = (l>>4)*8 + j], j=0..7
// B layout: lane l holds B[k = (l>>4)*8 + j][n = l&15]
// C/D layout: col = l&15, row = (l>>4)*4 + reg   [m89-verified]

__global__ __launch_bounds__(256) void k_gemm1(const float* __restrict__ x,
                                               const float* __restrict__ W1,
                                               const float* __restrict__ dis,
                                               u16* __restrict__ hs1) {
  int wid = (blockIdx.x * 256 + threadIdx.x) >> 6;   // wave id = 16-row tile
  if (wid >= NTILE) return;
  int l = threadIdx.x & 63;
  int m = l & 15, q = l >> 4;
  // B fragments: 4 kslices x 2 col-halves, preloaded to regs (W1 is L1/L2 hot)
  f16x8 B[4][2];
#pragma unroll
  for (int s = 0; s < 4; ++s)
#pragma unroll
    for (int h = 0; h < 2; ++h)
#pragma unroll
      for (int j = 0; j < 8; ++j)
        B[s][h][j] = (f16)W1[(s * 32 + q * 8 + j) * EMB + h * 16 + m];
  int row = wid * 16 + m;
  const float* xr = x + (size_t)row * FEAT + q * 8;
  f32x4 acc0 = {0.f, 0.f, 0.f, 0.f}, acc1 = {0.f, 0.f, 0.f, 0.f};
#pragma unroll
  for (int s = 0; s < 4; ++s) {
    f32x4 xa = __builtin_nontemporal_load((const f32x4*)(xr + s * 32));
    f32x4 xb = __builtin_nontemporal_load((const f32x4*)(xr + s * 32 + 4));
    f16x8 A;
    A[0] = (f16)xa.x; A[1] = (f16)xa.y; A[2] = (f16)xa.z; A[3] = (f16)xa.w;
    A[4] = (f16)xb.x; A[5] = (f16)xb.y; A[6] = (f16)xb.z; A[7] = (f16)xb.w;
    acc0 = __builtin_amdgcn_mfma_f32_16x16x32_f16(A, B[s][0], acc0, 0, 0, 0);
    acc1 = __builtin_amdgcn_mfma_f32_16x16x32_f16(A, B[s][1], acc1, 0, 0, 0);
  }
  f32x4 dq = *(const f32x4*)(dis + wid * 16 + q * 4);  // rows q*4..q*4+3 (broadcast)
  u16* o = hs1 + (size_t)(wid * 16) * EMB;
#pragma unroll
  for (int i = 0; i < 4; ++i) {
    int r = q * 4 + i;
    float dv = (i == 0) ? dq.x : (i == 1) ? dq.y : (i == 2) ? dq.z : dq.w;
    o[(size_t)r * EMB + m]      = __half_as_ushort(__float2half_rn(acc0[i] * dv));
    o[(size_t)r * EMB + 16 + m] = __half_as_ushort(__float2half_rn(acc1[i] * dv));
  }
}

__global__ __launch_bounds__(256) void k_gemm2(const u16* __restrict__ in1,
                                               const float* __restrict__ W2,
                                               const float* __restrict__ dis,
                                               u16* __restrict__ hs2) {
  int wid = (blockIdx.x * 256 + threadIdx.x) >> 6;
  if (wid >= NTILE) return;
  int l = threadIdx.x & 63;
  int m = l & 15, q = l >> 4;
  f16x8 B[2];
#pragma unroll
  for (int h = 0; h < 2; ++h)
#pragma unroll
    for (int j = 0; j < 8; ++j)
      B[h][j] = (f16)W2[(q * 8 + j) * EMB + h * 16 + m];
  int row = wid * 16 + m;
  f16x8 A = *(const f16x8*)(in1 + (size_t)row * EMB + q * 8);  // fp16 bits in u16
  f32x4 acc0 = {0.f, 0.f, 0.f, 0.f}, acc1 = {0.f, 0.f, 0.f, 0.f};
  acc0 = __builtin_amdgcn_mfma_f32_16x16x32_f16(A, B[0], acc0, 0, 0, 0);
  acc1 = __builtin_amdgcn_mfma_f32_16x16x32_f16(A, B[1], acc1, 0, 0, 0);
  f32x4 dq = *(const f32x4*)(dis + wid * 16 + q * 4);
  u16* o = hs2 + (size_t)(wid * 16) * EMB;
#pragma unroll
  for (int i = 0; i < 4; ++i) {
    int r = q * 4 + i;
    float dv = (i == 0) ? dq.x : (i == 1) ? dq.y : (i == 2) ? dq.z : dq.w;
    o[(size_t)r * EMB + m]      = __half_as_ushort(__float2half_rn(acc0[i] * dv));
    o[(size_t)r * EMB + 16 + m] = __half_as_ushort(__float2half_rn(acc1[i] * dv));
  }
}

// ---------------- Aggregation: wave-per-node, 8 rows per gather instruction ----------------

__device__ __forceinline__ float4 agg_row_wide(const u16* __restrict__ hs,
                                               const int* __restrict__ row_ptr,
                                               const int* __restrict__ col,
                                               int n, int g, int sub) {
  const u16x4* hs4 = (const u16x4*)hs;
  int e0 = row_ptr[n], e1 = row_ptr[n + 1];   // multiple of 8 apart
  int nch = (e1 - e0) >> 3;
  int ec = e0 + g;
  float4 acc = make_float4(0.f, 0.f, 0.f, 0.f);
  int s0 = (nch > 0) ? __builtin_nontemporal_load(&col[ec]) : ZROW;
  int s1 = (nch > 1) ? __builtin_nontemporal_load(&col[ec + 8]) : ZROW;
  int i = 0;
  for (; i + 2 <= nch; i += 2) {
    u16x4 va = hs4[(size_t)s0 * 8 + sub];
    u16x4 vb = hs4[(size_t)s1 * 8 + sub];
    int t0 = (i + 2 < nch) ? __builtin_nontemporal_load(&col[ec + (i + 2) * 8]) : ZROW;
    int t1 = (i + 3 < nch) ? __builtin_nontemporal_load(&col[ec + (i + 3) * 8]) : ZROW;
    float4 fa = h4_to_f4(va);
    float4 fb = h4_to_f4(vb);
    acc.x += fa.x + fb.x;
    acc.y += fa.y + fb.y;
    acc.z += fa.z + fb.z;
    acc.w += fa.w + fb.w;
    s0 = t0;
    s1 = t1;
  }
  if (i < nch) {
    float4 fa = h4_to_f4(hs4[(size_t)s0 * 8 + sub]);
    acc.x += fa.x; acc.y += fa.y; acc.z += fa.z; acc.w += fa.w;
  }
#pragma unroll
  for (int mm = 8; mm < 64; mm <<= 1) {
    acc.x += __shfl_xor(acc.x, mm);
    acc.y += __shfl_xor(acc.y, mm);
    acc.z += __shfl_xor(acc.z, mm);
    acc.w += __shfl_xor(acc.w, mm);
  }
  // self-loop (hs already dis-scaled); added post-reduction => counted once
  float4 sf = h4_to_f4(hs4[(size_t)n * 8 + sub]);
  acc.x += sf.x; acc.y += sf.y; acc.z += sf.z; acc.w += sf.w;
  return acc;
}

__global__ __launch_bounds__(256) void k_agg1(const u16* __restrict__ hs,
                                              const int* __restrict__ row_ptr,
                                              const int* __restrict__ col,
                                              const float* __restrict__ dis,
                                              const float* __restrict__ b,
                                              u16* __restrict__ out) {
  int t = threadIdx.x;
  int n = blockIdx.x * 4 + (t >> 6);
  int l = t & 63;
  int g = (l >> 3), sub = l & 7;
  float4 acc = agg_row_wide(hs, row_ptr, col, n, g, sub);
  if (g == 0) {
    float d = dis[n];
    float4 bq = ((const float4*)b)[sub];
    float4 o;
    o.x = fmaxf(fmaf(acc.x, d, bq.x), 0.f);
    o.y = fmaxf(fmaf(acc.y, d, bq.y), 0.f);
    o.z = fmaxf(fmaf(acc.z, d, bq.z), 0.f);
    o.w = fmaxf(fmaf(acc.w, d, bq.w), 0.f);
    ((u16x4*)(out + (size_t)n * EMB))[sub] = f4_to_h4(o);
  }
}

// pooling tail: privatized 64-copy accumulator kills same-line atomic contention
__global__ __launch_bounds__(256) void k_agg2pool(const u16* __restrict__ hs,
                                                  const int* __restrict__ row_ptr,
                                                  const int* __restrict__ col,
                                                  const float* __restrict__ dis,
                                                  const float* __restrict__ b2,
                                                  const float* __restrict__ Wo,
                                                  const int* __restrict__ batch,
                                                  float* __restrict__ gaccP) {
  int t = threadIdx.x;
  int n = blockIdx.x * 4 + (t >> 6);
  int l = t & 63;
  int g = (l >> 3), sub = l & 7;
  float4 acc = agg_row_wide(hs, row_ptr, col, n, g, sub);
  float d = dis[n];
  float4 bq = ((const float4*)b2)[sub];
  float4 wq = ((const float4*)Wo)[sub];
  float p = fmaxf(fmaf(acc.x, d, bq.x), 0.f) * wq.x
          + fmaxf(fmaf(acc.y, d, bq.y), 0.f) * wq.y
          + fmaxf(fmaf(acc.z, d, bq.z), 0.f) * wq.z
          + fmaxf(fmaf(acc.w, d, bq.w), 0.f) * wq.w;
  p += __shfl_xor(p, 1);
  p += __shfl_xor(p, 2);
  p += __shfl_xor(p, 4);
  if (l == 0) {
    int copy = blockIdx.x & (NCOPY - 1);   // consecutive blocks -> different copies
    atomicAdd(&gaccP[copy * N_GRAPHS + batch[n]], p);
  }
}

__global__ __launch_bounds__(256) void k_finalize(const float* __restrict__ gaccP,
                                                  const int* __restrict__ gcnt,
                                                  const float* __restrict__ bo,
                                                  float* __restrict__ out) {
  int g = blockIdx.x * 256 + threadIdx.x;
  if (g < N_GRAPHS) {
    float s = 0.f;
#pragma unroll 8
    for (int c = 0; c < NCOPY; ++c) s += gaccP[c * N_GRAPHS + g];
    out[g] = s / fmaxf((float)gcnt[g], 1.0f) + bo[0];
  }
}

// ---------------- launch ----------------

extern "C" void kernel_launch(void* const* d_in, const int* in_sizes, int n_in,
                              void* d_out, int out_size, void* d_ws, size_t ws_size,
                              hipStream_t stream) {
  const float* x     = (const float*)d_in[0];
  const int*   ei    = (const int*)d_in[1];   // [2, E]: src then dst
  const int*   batch = (const int*)d_in[2];
  const float* W1    = (const float*)d_in[3];
  const float* b1    = (const float*)d_in[4];
  const float* W2    = (const float*)d_in[5];
  const float* b2    = (const float*)d_in[6];
  const float* Wo    = (const float*)d_in[7];
  const float* bo    = (const float*)d_in[8];
  float* out = (float*)d_out;

  const int* src = ei;
  const int* dst = ei + N_EDGES;

  char* w = (char*)d_ws;
  int*   degcnt  = (int*)w;    w += (size_t)N_NODES * 4;            // zeroed
  float* gaccP   = (float*)w;  w += (size_t)NCOPY * N_GRAPHS * 4;   // zeroed
  size_t zero_bytes = (size_t)(w - (char*)d_ws);
  int*   gcnt    = (int*)w;    w += (size_t)N_GRAPHS * 4;
  int*   row_ptr = (int*)w;    w += (size_t)(N_NODES + 4) * 4;
  int*   blocksum= (int*)w;    w += 128 * 4;
  int*   blockoff= (int*)w;    w += 128 * 4;
  int*   cnt     = (int*)w;    w += (size_t)ABLK * NBKT * 4;
  int*   boff    = (int*)w;    w += (size_t)ABLK * NBKT * 4;
  int*   btot    = (int*)w;    w += (size_t)(NBKT + 8) * 4;
  int*   bbase   = (int*)w;    w += (size_t)(NBKT + 8) * 4;
  int*   col     = (int*)w;    w += (size_t)PADCAP * 4;
  float* dis     = (float*)w;  w += (size_t)N_NODES * 4;
  u16*   hs1     = (u16*)w;    w += (size_t)(N_NODES + 1) * EMB * 2;  // +1 zero row
  u16*   out1    = (u16*)w;    w += (size_t)N_NODES * EMB * 2;        // 6.4 MB
  u32*   binbuf  = (u32*)out1;  // alias: binbuf dead before agg1 writes out1
  u16*   hs2     = hs1;         // hs1 dead after agg1; zero row persists

  const int EB = (N_EDGES + 255) / 256;    // 6250
  const int NB = (N_NODES + 255) / 256;    // 391
  const int SB = (N_NODES + 1023) / 1024;  // 98
  const int GB = (NTILE * 64 + 255) / 256; // 1563 MFMA blocks
  const int AB = N_NODES / 4;              // 25000 wave-per-node blocks

  (void)hipMemsetAsync(d_ws, 0, zero_bytes, stream);

  k_hist<<<EB, 256, 0, stream>>>(dst, degcnt);
  k_node_init<<<NB, 256, 0, stream>>>(degcnt, dis, hs1);
  k_gcnt<<<1, 512, 0, stream>>>(batch, gcnt);
  k_scanA<<<SB, 256, 0, stream>>>(degcnt, blocksum);
  k_scanB<<<1, 128, 0, stream>>>(blocksum, blockoff, row_ptr + N_NODES, SB);
  k_scanC<<<SB, 256, 0, stream>>>(degcnt, blockoff, row_ptr);

  k_binA<<<ABLK, 256, 0, stream>>>(dst, cnt);
  k_binscanA<<<NBKT, 128, 0, stream>>>(cnt, boff, btot);
  k_binscanB<<<1, 256, 0, stream>>>(btot, bbase);
  k_binscat<<<ABLK, 256, 0, stream>>>(src, dst, boff, bbase, binbuf);
  k_fillB<<<NBKT, 256, 0, stream>>>(binbuf, bbase, row_ptr, col);

  k_gemm1<<<GB, 256, 0, stream>>>(x, W1, dis, hs1);
  k_agg1<<<AB, 256, 0, stream>>>(hs1, row_ptr, col, dis, b1, out1);
  k_gemm2<<<GB, 256, 0, stream>>>(out1, W2, dis, hs2);
  k_agg2pool<<<AB, 256, 0, stream>>>(hs2, row_ptr, col, dis, b2, Wo, batch, gaccP);
  k_finalize<<<2, 256, 0, stream>>>(gaccP, gcnt, bo, out);
}

// Round 11
// 301.518 us; speedup vs baseline: 2.7933x; 1.1910x over previous
//
#include <hip/hip_runtime.h>
#include <hip/hip_fp16.h>

#define N_NODES 100000
#define N_EDGES 1600000
#define N_GRAPHS 512
#define FEAT 128
#define EMB 32
#define ZROW N_NODES                        // dedicated zero row for padding
#define PADCAP (N_EDGES + 8 * N_NODES)      // pad8 worst-case col slots
#define NCOPY 64                            // privatized pool accumulator copies
#define NBKT 250                            // dst buckets (400 nodes each)
#define NPB 400                             // nodes per bucket
#define ABLK 128                            // bin phase blocks
#define EPB (N_EDGES / ABLK)                // 12500 edges per bin block
#define NTILE (N_NODES / 16)                // 6250 MFMA row tiles

typedef unsigned short u16;
typedef unsigned int u32;
typedef _Float16 f16;
typedef float f32x4 __attribute__((ext_vector_type(4)));
typedef unsigned short u16x4 __attribute__((ext_vector_type(4)));
typedef f16 f16x8 __attribute__((ext_vector_type(8)));

__device__ __forceinline__ int pad8(int d) { return (d + 7) & ~7; }

__device__ __forceinline__ float4 h4_to_f4(u16x4 v) {
  union { unsigned int u; __half2 h; } a, b;
  a.u = (unsigned int)v.x | ((unsigned int)v.y << 16);
  b.u = (unsigned int)v.z | ((unsigned int)v.w << 16);
  float2 f0 = __half22float2(a.h);
  float2 f1 = __half22float2(b.h);
  return make_float4(f0.x, f0.y, f1.x, f1.y);
}

__device__ __forceinline__ u16x4 f4_to_h4(float4 f) {
  union { unsigned int u; __half2 h; } a, b;
  a.h = __float22half2_rn(make_float2(f.x, f.y));
  b.h = __float22half2_rn(make_float2(f.z, f.w));
  u16x4 r;
  r.x = (u16)(a.u & 0xffff); r.y = (u16)(a.u >> 16);
  r.z = (u16)(b.u & 0xffff); r.w = (u16)(b.u >> 16);
  return r;
}

// ---------------- misc ----------------

// pure elementwise; also zero the fp16 zero-row of hs1
__global__ __launch_bounds__(256) void k_node_init(const int* __restrict__ degcnt,
                                                   float* __restrict__ dis,
                                                   u16* __restrict__ hs1) {
  int i = blockIdx.x * 256 + threadIdx.x;
  if (i < N_NODES) dis[i] = rsqrtf((float)degcnt[i] + 1.0f);
  if (i < EMB) hs1[(size_t)ZROW * EMB + i] = 0;
}

// batch is sorted: per-graph counts via binary search, zero atomics
__global__ __launch_bounds__(512) void k_gcnt(const int* __restrict__ batch,
                                              int* __restrict__ gcnt) {
  __shared__ int first[N_GRAPHS + 1];
  int g = threadIdx.x;
  int lo = 0, hi = N_NODES;
  while (lo < hi) {
    int mid = (lo + hi) >> 1;
    if (batch[mid] < g) lo = mid + 1; else hi = mid;
  }
  first[g] = lo;
  if (g == 0) first[N_GRAPHS] = N_NODES;
  __syncthreads();
  gcnt[g] = first[g + 1] - first[g];
}

// ---------------- row_ptr scans (over pad8(deg)) ----------------

__global__ __launch_bounds__(256) void k_scanA(const int* __restrict__ degcnt,
                                               int* __restrict__ blocksum) {
  __shared__ int sh[256];
  int t = threadIdx.x;
  int base = blockIdx.x * 1024;
  int s = 0;
#pragma unroll
  for (int j = 0; j < 4; j++) {
    int idx = base + t * 4 + j;
    if (idx < N_NODES) s += pad8(degcnt[idx]);
  }
  sh[t] = s;
  __syncthreads();
  for (int off = 128; off > 0; off >>= 1) {
    if (t < off) sh[t] += sh[t + off];
    __syncthreads();
  }
  if (t == 0) blocksum[blockIdx.x] = sh[0];
}

__global__ __launch_bounds__(128) void k_scanB(const int* __restrict__ blocksum,
                                               int* __restrict__ blockoff,
                                               int* __restrict__ total_out, int nb) {
  __shared__ int sh[128];
  int t = threadIdx.x;
  int v = (t < nb) ? blocksum[t] : 0;
  sh[t] = v;
  __syncthreads();
  for (int off = 1; off < 128; off <<= 1) {
    int add = (t >= off) ? sh[t - off] : 0;
    __syncthreads();
    sh[t] += add;
    __syncthreads();
  }
  if (t < nb) blockoff[t] = sh[t] - v;   // exclusive
  if (t == nb - 1) total_out[0] = sh[t];
}

__global__ __launch_bounds__(256) void k_scanC(const int* __restrict__ degcnt,
                                               const int* __restrict__ blockoff,
                                               int* __restrict__ row_ptr) {
  __shared__ int sh[256];
  int t = threadIdx.x;
  int base = blockIdx.x * 1024;
  int v[4];
#pragma unroll
  for (int j = 0; j < 4; j++) {
    int idx = base + t * 4 + j;
    v[j] = (idx < N_NODES) ? pad8(degcnt[idx]) : 0;
  }
  int tsum = v[0] + v[1] + v[2] + v[3];
  sh[t] = tsum;
  __syncthreads();
  for (int off = 1; off < 256; off <<= 1) {
    int add = (t >= off) ? sh[t - off] : 0;
    __syncthreads();
    sh[t] += add;
    __syncthreads();
  }
  int p = sh[t] - tsum + blockoff[blockIdx.x];
#pragma unroll
  for (int j = 0; j < 4; j++) {
    int idx = base + t * 4 + j;
    if (idx < N_NODES) row_ptr[idx] = p;
    p += v[j];
  }
}

// ---------------- two-phase binned CSR fill (also produces degcnt) ----------------

__global__ __launch_bounds__(256) void k_binA(const int* __restrict__ dst,
                                              int* __restrict__ cnt) {
  __shared__ int h[NBKT];
  int k = blockIdx.x, t = threadIdx.x;
  for (int i = t; i < NBKT; i += 256) h[i] = 0;
  __syncthreads();
  int e0 = k * EPB;
  for (int e = e0 + t; e < e0 + EPB; e += 256)
    atomicAdd(&h[(u32)dst[e] / (u32)NPB], 1);
  __syncthreads();
  for (int i = t; i < NBKT; i += 256) cnt[k * NBKT + i] = h[i];
}

__global__ __launch_bounds__(128) void k_binscanA(const int* __restrict__ cnt,
                                                  int* __restrict__ off,
                                                  int* __restrict__ tot) {
  __shared__ int sh[128];
  int b = blockIdx.x, t = threadIdx.x;
  int v = cnt[t * NBKT + b];
  sh[t] = v;
  __syncthreads();
  for (int o = 1; o < 128; o <<= 1) {
    int add = (t >= o) ? sh[t - o] : 0;
    __syncthreads();
    sh[t] += add;
    __syncthreads();
  }
  off[t * NBKT + b] = sh[t] - v;
  if (t == 127) tot[b] = sh[127];
}

__global__ __launch_bounds__(256) void k_binscanB(const int* __restrict__ tot,
                                                  int* __restrict__ base) {
  __shared__ int sh[256];
  int t = threadIdx.x;
  int v = (t < NBKT) ? tot[t] : 0;
  sh[t] = v;
  __syncthreads();
  for (int o = 1; o < 256; o <<= 1) {
    int add = (t >= o) ? sh[t - o] : 0;
    __syncthreads();
    sh[t] += add;
    __syncthreads();
  }
  if (t < NBKT) base[t] = sh[t] - v;
  if (t == NBKT - 1) base[NBKT] = sh[t];
}

__global__ __launch_bounds__(256) void k_binscat(const int* __restrict__ src,
                                                 const int* __restrict__ dst,
                                                 const int* __restrict__ off,
                                                 const int* __restrict__ base,
                                                 u32* __restrict__ binbuf) {
  __shared__ int posB[NBKT];
  __shared__ int h[NBKT];
  int k = blockIdx.x, t = threadIdx.x;
  for (int i = t; i < NBKT; i += 256) {
    posB[i] = base[i] + off[k * NBKT + i];
    h[i] = 0;
  }
  __syncthreads();
  int e0 = k * EPB;
  for (int e = e0 + t; e < e0 + EPB; e += 256) {
    u32 d = (u32)dst[e];
    int b = d / (u32)NPB;
    int r = atomicAdd(&h[b], 1);
    binbuf[posB[b] + r] = (u32)src[e] * (u32)NPB + (d - (u32)b * NPB);
  }
}

// degree histogram from binned data: LDS counters only, zero global atomics
// (replaces k_hist, whose 1.6M cross-XCD atomics cost 65 µs / 50 MB writeback)
__global__ __launch_bounds__(256) void k_bdeg(const u32* __restrict__ binbuf,
                                              const int* __restrict__ base,
                                              int* __restrict__ degcnt) {
  __shared__ int c[NPB];
  int b = blockIdx.x, t = threadIdx.x;
  for (int i = t; i < NPB; i += 256) c[i] = 0;
  __syncthreads();
  int s0 = base[b], s1 = base[b + 1];
  for (int i = s0 + t; i < s1; i += 256) {
    u32 p = binbuf[i];
    u32 s = p / (u32)NPB;
    atomicAdd(&c[p - s * (u32)NPB], 1);
  }
  __syncthreads();
  for (int i = t; i < NPB; i += 256) degcnt[b * NPB + i] = c[i];
}

__global__ __launch_bounds__(256) void k_fillB(const u32* __restrict__ binbuf,
                                               const int* __restrict__ base,
                                               const int* __restrict__ row_ptr,
                                               int* __restrict__ col) {
  __shared__ int rp[NPB + 1];
  __shared__ int cur[NPB];
  int b = blockIdx.x, t = threadIdx.x;
  for (int i = t; i < NPB + 1; i += 256) rp[i] = row_ptr[b * NPB + i];
  for (int i = t; i < NPB; i += 256) cur[i] = 0;
  __syncthreads();
  int s0 = base[b], s1 = base[b + 1];
  for (int i = s0 + t; i < s1; i += 256) {
    u32 p = binbuf[i];
    u32 s = p / (u32)NPB;
    int ld = p - s * (u32)NPB;
    int pos = atomicAdd(&cur[ld], 1);
    col[rp[ld] + pos] = (int)s;
  }
  __syncthreads();
  for (int ld = t; ld < NPB; ld += 256) {
    int bs = rp[ld], len = rp[ld + 1] - bs, c = cur[ld];
    for (int j = c; j < len; j++) col[bs + j] = ZROW;
  }
}

// ---------------- GEMMs via MFMA 16x16x32 f16 (W in register B-frags) ----------------
// A layout: lane l holds A[m = l&15][k = (l>>4)*8 + j], j=0..7
// B layout: lane l holds B[k = (l>>4)*8 + j][n = l&15]
// C/D layout: col = l&15, row = (l>>4)*4 + reg   [m89-verified]

__global__ __launch_bounds__(256) void k_gemm1(const float* __restrict__ x,
                                               const float* __restrict__ W1,
                                               const float* __restrict__ dis,
                                               u16* __restrict__ hs1) {
  int wid = (blockIdx.x * 256 + threadIdx.x) >> 6;   // wave id = 16-row tile
  if (wid >= NTILE) return;
  int l = threadIdx.x & 63;
  int m = l & 15, q = l >> 4;
  f16x8 B[4][2];
#pragma unroll
  for (int s = 0; s < 4; ++s)
#pragma unroll
    for (int h = 0; h < 2; ++h)
#pragma unroll
      for (int j = 0; j < 8; ++j)
        B[s][h][j] = (f16)W1[(s * 32 + q * 8 + j) * EMB + h * 16 + m];
  int row = wid * 16 + m;
  const float* xr = x + (size_t)row * FEAT + q * 8;
  f32x4 acc0 = {0.f, 0.f, 0.f, 0.f}, acc1 = {0.f, 0.f, 0.f, 0.f};
#pragma unroll
  for (int s = 0; s < 4; ++s) {
    f32x4 xa = __builtin_nontemporal_load((const f32x4*)(xr + s * 32));
    f32x4 xb = __builtin_nontemporal_load((const f32x4*)(xr + s * 32 + 4));
    f16x8 A;
    A[0] = (f16)xa.x; A[1] = (f16)xa.y; A[2] = (f16)xa.z; A[3] = (f16)xa.w;
    A[4] = (f16)xb.x; A[5] = (f16)xb.y; A[6] = (f16)xb.z; A[7] = (f16)xb.w;
    acc0 = __builtin_amdgcn_mfma_f32_16x16x32_f16(A, B[s][0], acc0, 0, 0, 0);
    acc1 = __builtin_amdgcn_mfma_f32_16x16x32_f16(A, B[s][1], acc1, 0, 0, 0);
  }
  f32x4 dq = *(const f32x4*)(dis + wid * 16 + q * 4);
  u16* o = hs1 + (size_t)(wid * 16) * EMB;
#pragma unroll
  for (int i = 0; i < 4; ++i) {
    int r = q * 4 + i;
    float dv = (i == 0) ? dq.x : (i == 1) ? dq.y : (i == 2) ? dq.z : dq.w;
    o[(size_t)r * EMB + m]      = __half_as_ushort(__float2half_rn(acc0[i] * dv));
    o[(size_t)r * EMB + 16 + m] = __half_as_ushort(__float2half_rn(acc1[i] * dv));
  }
}

__global__ __launch_bounds__(256) void k_gemm2(const u16* __restrict__ in1,
                                               const float* __restrict__ W2,
                                               const float* __restrict__ dis,
                                               u16* __restrict__ hs2) {
  int wid = (blockIdx.x * 256 + threadIdx.x) >> 6;
  if (wid >= NTILE) return;
  int l = threadIdx.x & 63;
  int m = l & 15, q = l >> 4;
  f16x8 B[2];
#pragma unroll
  for (int h = 0; h < 2; ++h)
#pragma unroll
    for (int j = 0; j < 8; ++j)
      B[h][j] = (f16)W2[(q * 8 + j) * EMB + h * 16 + m];
  int row = wid * 16 + m;
  f16x8 A = *(const f16x8*)(in1 + (size_t)row * EMB + q * 8);
  f32x4 acc0 = {0.f, 0.f, 0.f, 0.f}, acc1 = {0.f, 0.f, 0.f, 0.f};
  acc0 = __builtin_amdgcn_mfma_f32_16x16x32_f16(A, B[0], acc0, 0, 0, 0);
  acc1 = __builtin_amdgcn_mfma_f32_16x16x32_f16(A, B[1], acc1, 0, 0, 0);
  f32x4 dq = *(const f32x4*)(dis + wid * 16 + q * 4);
  u16* o = hs2 + (size_t)(wid * 16) * EMB;
#pragma unroll
  for (int i = 0; i < 4; ++i) {
    int r = q * 4 + i;
    float dv = (i == 0) ? dq.x : (i == 1) ? dq.y : (i == 2) ? dq.z : dq.w;
    o[(size_t)r * EMB + m]      = __half_as_ushort(__float2half_rn(acc0[i] * dv));
    o[(size_t)r * EMB + 16 + m] = __half_as_ushort(__float2half_rn(acc1[i] * dv));
  }
}

// ---------------- Aggregation: wave-per-node, 8 rows per gather instruction ----------------

__device__ __forceinline__ float4 agg_row_wide(const u16* __restrict__ hs,
                                               const int* __restrict__ row_ptr,
                                               const int* __restrict__ col,
                                               int n, int g, int sub) {
  const u16x4* hs4 = (const u16x4*)hs;
  int e0 = row_ptr[n], e1 = row_ptr[n + 1];   // multiple of 8 apart
  int nch = (e1 - e0) >> 3;
  int ec = e0 + g;
  float4 acc = make_float4(0.f, 0.f, 0.f, 0.f);
  int s0 = (nch > 0) ? __builtin_nontemporal_load(&col[ec]) : ZROW;
  int s1 = (nch > 1) ? __builtin_nontemporal_load(&col[ec + 8]) : ZROW;
  int i = 0;
  for (; i + 2 <= nch; i += 2) {
    u16x4 va = hs4[(size_t)s0 * 8 + sub];
    u16x4 vb = hs4[(size_t)s1 * 8 + sub];
    int t0 = (i + 2 < nch) ? __builtin_nontemporal_load(&col[ec + (i + 2) * 8]) : ZROW;
    int t1 = (i + 3 < nch) ? __builtin_nontemporal_load(&col[ec + (i + 3) * 8]) : ZROW;
    float4 fa = h4_to_f4(va);
    float4 fb = h4_to_f4(vb);
    acc.x += fa.x + fb.x;
    acc.y += fa.y + fb.y;
    acc.z += fa.z + fb.z;
    acc.w += fa.w + fb.w;
    s0 = t0;
    s1 = t1;
  }
  if (i < nch) {
    float4 fa = h4_to_f4(hs4[(size_t)s0 * 8 + sub]);
    acc.x += fa.x; acc.y += fa.y; acc.z += fa.z; acc.w += fa.w;
  }
#pragma unroll
  for (int mm = 8; mm < 64; mm <<= 1) {
    acc.x += __shfl_xor(acc.x, mm);
    acc.y += __shfl_xor(acc.y, mm);
    acc.z += __shfl_xor(acc.z, mm);
    acc.w += __shfl_xor(acc.w, mm);
  }
  // self-loop (hs already dis-scaled); added post-reduction => counted once
  float4 sf = h4_to_f4(hs4[(size_t)n * 8 + sub]);
  acc.x += sf.x; acc.y += sf.y; acc.z += sf.z; acc.w += sf.w;
  return acc;
}

__global__ __launch_bounds__(256) void k_agg1(const u16* __restrict__ hs,
                                              const int* __restrict__ row_ptr,
                                              const int* __restrict__ col,
                                              const float* __restrict__ dis,
                                              const float* __restrict__ b,
                                              u16* __restrict__ out) {
  int t = threadIdx.x;
  int n = blockIdx.x * 4 + (t >> 6);
  int l = t & 63;
  int g = (l >> 3), sub = l & 7;
  float4 acc = agg_row_wide(hs, row_ptr, col, n, g, sub);
  if (g == 0) {
    float d = dis[n];
    float4 bq = ((const float4*)b)[sub];
    float4 o;
    o.x = fmaxf(fmaf(acc.x, d, bq.x), 0.f);
    o.y = fmaxf(fmaf(acc.y, d, bq.y), 0.f);
    o.z = fmaxf(fmaf(acc.z, d, bq.z), 0.f);
    o.w = fmaxf(fmaf(acc.w, d, bq.w), 0.f);
    ((u16x4*)(out + (size_t)n * EMB))[sub] = f4_to_h4(o);
  }
}

// pooling tail: privatized 64-copy accumulator kills same-line atomic contention
__global__ __launch_bounds__(256) void k_agg2pool(const u16* __restrict__ hs,
                                                  const int* __restrict__ row_ptr,
                                                  const int* __restrict__ col,
                                                  const float* __restrict__ dis,
                                                  const float* __restrict__ b2,
                                                  const float* __restrict__ Wo,
                                                  const int* __restrict__ batch,
                                                  float* __restrict__ gaccP) {
  int t = threadIdx.x;
  int n = blockIdx.x * 4 + (t >> 6);
  int l = t & 63;
  int g = (l >> 3), sub = l & 7;
  float4 acc = agg_row_wide(hs, row_ptr, col, n, g, sub);
  float d = dis[n];
  float4 bq = ((const float4*)b2)[sub];
  float4 wq = ((const float4*)Wo)[sub];
  float p = fmaxf(fmaf(acc.x, d, bq.x), 0.f) * wq.x
          + fmaxf(fmaf(acc.y, d, bq.y), 0.f) * wq.y
          + fmaxf(fmaf(acc.z, d, bq.z), 0.f) * wq.z
          + fmaxf(fmaf(acc.w, d, bq.w), 0.f) * wq.w;
  p += __shfl_xor(p, 1);
  p += __shfl_xor(p, 2);
  p += __shfl_xor(p, 4);
  if (l == 0) {
    int copy = blockIdx.x & (NCOPY - 1);
    atomicAdd(&gaccP[copy * N_GRAPHS + batch[n]], p);
  }
}

__global__ __launch_bounds__(256) void k_finalize(const float* __restrict__ gaccP,
                                                  const int* __restrict__ gcnt,
                                                  const float* __restrict__ bo,
                                                  float* __restrict__ out) {
  int g = blockIdx.x * 256 + threadIdx.x;
  if (g < N_GRAPHS) {
    float s = 0.f;
#pragma unroll 8
    for (int c = 0; c < NCOPY; ++c) s += gaccP[c * N_GRAPHS + g];
    out[g] = s / fmaxf((float)gcnt[g], 1.0f) + bo[0];
  }
}

// ---------------- launch ----------------

extern "C" void kernel_launch(void* const* d_in, const int* in_sizes, int n_in,
                              void* d_out, int out_size, void* d_ws, size_t ws_size,
                              hipStream_t stream) {
  const float* x     = (const float*)d_in[0];
  const int*   ei    = (const int*)d_in[1];   // [2, E]: src then dst
  const int*   batch = (const int*)d_in[2];
  const float* W1    = (const float*)d_in[3];
  const float* b1    = (const float*)d_in[4];
  const float* W2    = (const float*)d_in[5];
  const float* b2    = (const float*)d_in[6];
  const float* Wo    = (const float*)d_in[7];
  const float* bo    = (const float*)d_in[8];
  float* out = (float*)d_out;

  const int* src = ei;
  const int* dst = ei + N_EDGES;

  char* w = (char*)d_ws;
  float* gaccP   = (float*)w;  w += (size_t)NCOPY * N_GRAPHS * 4;   // zeroed
  size_t zero_bytes = (size_t)(w - (char*)d_ws);
  int*   degcnt  = (int*)w;    w += (size_t)N_NODES * 4;            // written by k_bdeg
  int*   gcnt    = (int*)w;    w += (size_t)N_GRAPHS * 4;
  int*   row_ptr = (int*)w;    w += (size_t)(N_NODES + 4) * 4;
  int*   blocksum= (int*)w;    w += 128 * 4;
  int*   blockoff= (int*)w;    w += 128 * 4;
  int*   cnt     = (int*)w;    w += (size_t)ABLK * NBKT * 4;
  int*   boff    = (int*)w;    w += (size_t)ABLK * NBKT * 4;
  int*   btot    = (int*)w;    w += (size_t)(NBKT + 8) * 4;
  int*   bbase   = (int*)w;    w += (size_t)(NBKT + 8) * 4;
  int*   col     = (int*)w;    w += (size_t)PADCAP * 4;
  float* dis     = (float*)w;  w += (size_t)N_NODES * 4;
  u16*   hs1     = (u16*)w;    w += (size_t)(N_NODES + 1) * EMB * 2;  // +1 zero row
  u16*   out1    = (u16*)w;    w += (size_t)N_NODES * EMB * 2;        // 6.4 MB
  u32*   binbuf  = (u32*)out1;  // alias: binbuf dead before agg1 writes out1
  u16*   hs2     = hs1;         // hs1 dead after agg1; zero row persists

  const int NB = (N_NODES + 255) / 256;    // 391
  const int SB = (N_NODES + 1023) / 1024;  // 98
  const int GB = (NTILE * 64 + 255) / 256; // 1563 MFMA blocks
  const int AB = N_NODES / 4;              // 25000 wave-per-node blocks

  (void)hipMemsetAsync(d_ws, 0, zero_bytes, stream);

  // bin pipeline first: it now also produces the degree histogram
  k_binA<<<ABLK, 256, 0, stream>>>(dst, cnt);
  k_binscanA<<<NBKT, 128, 0, stream>>>(cnt, boff, btot);
  k_binscanB<<<1, 256, 0, stream>>>(btot, bbase);
  k_binscat<<<ABLK, 256, 0, stream>>>(src, dst, boff, bbase, binbuf);
  k_bdeg<<<NBKT, 256, 0, stream>>>(binbuf, bbase, degcnt);

  k_node_init<<<NB, 256, 0, stream>>>(degcnt, dis, hs1);
  k_gcnt<<<1, 512, 0, stream>>>(batch, gcnt);
  k_scanA<<<SB, 256, 0, stream>>>(degcnt, blocksum);
  k_scanB<<<1, 128, 0, stream>>>(blocksum, blockoff, row_ptr + N_NODES, SB);
  k_scanC<<<SB, 256, 0, stream>>>(degcnt, blockoff, row_ptr);
  k_fillB<<<NBKT, 256, 0, stream>>>(binbuf, bbase, row_ptr, col);

  k_gemm1<<<GB, 256, 0, stream>>>(x, W1, dis, hs1);
  k_agg1<<<AB, 256, 0, stream>>>(hs1, row_ptr, col, dis, b1, out1);
  k_gemm2<<<GB, 256, 0, stream>>>(out1, W2, dis, hs2);
  k_agg2pool<<<AB, 256, 0, stream>>>(hs2, row_ptr, col, dis, b2, Wo, batch, gaccP);
  k_finalize<<<2, 256, 0, stream>>>(gaccP, gcnt, bo, out);
}

// Round 12
// 278.036 us; speedup vs baseline: 3.0292x; 1.0845x over previous
//
#include <hip/hip_runtime.h>
#include <hip/hip_fp16.h>

#define N_NODES 100000
#define N_EDGES 1600000
#define N_GRAPHS 512
#define FEAT 128
#define EMB 32
#define ZROW N_NODES                        // dedicated zero row for padding
#define PADCAP (N_EDGES + 8 * N_NODES)      // pad8 worst-case col slots
#define NCOPY 64                            // privatized pool accumulator copies
#define NBKT 250                            // dst buckets (400 nodes each)
#define NPB 400                             // nodes per bucket
#define ABLK 1024                           // bin phase blocks (R11: was 128, occ 4.3%)
#define EPB 1563                            // ceil(N_EDGES / ABLK)
#define NTILE (N_NODES / 16)                // 6250 MFMA row tiles

typedef unsigned short u16;
typedef unsigned int u32;
typedef _Float16 f16;
typedef float f32x4 __attribute__((ext_vector_type(4)));
typedef unsigned short u16x4 __attribute__((ext_vector_type(4)));
typedef f16 f16x8 __attribute__((ext_vector_type(8)));

__device__ __forceinline__ int pad8(int d) { return (d + 7) & ~7; }

__device__ __forceinline__ float4 h4_to_f4(u16x4 v) {
  union { unsigned int u; __half2 h; } a, b;
  a.u = (unsigned int)v.x | ((unsigned int)v.y << 16);
  b.u = (unsigned int)v.z | ((unsigned int)v.w << 16);
  float2 f0 = __half22float2(a.h);
  float2 f1 = __half22float2(b.h);
  return make_float4(f0.x, f0.y, f1.x, f1.y);
}

__device__ __forceinline__ u16x4 f4_to_h4(float4 f) {
  union { unsigned int u; __half2 h; } a, b;
  a.h = __float22half2_rn(make_float2(f.x, f.y));
  b.h = __float22half2_rn(make_float2(f.z, f.w));
  u16x4 r;
  r.x = (u16)(a.u & 0xffff); r.y = (u16)(a.u >> 16);
  r.z = (u16)(b.u & 0xffff); r.w = (u16)(b.u >> 16);
  return r;
}

// ---------------- misc ----------------

// pure elementwise; also zero the fp16 zero-row of hs1
__global__ __launch_bounds__(256) void k_node_init(const int* __restrict__ degcnt,
                                                   float* __restrict__ dis,
                                                   u16* __restrict__ hs1) {
  int i = blockIdx.x * 256 + threadIdx.x;
  if (i < N_NODES) dis[i] = rsqrtf((float)degcnt[i] + 1.0f);
  if (i < EMB) hs1[(size_t)ZROW * EMB + i] = 0;
}

// batch is sorted: per-graph counts via binary search, zero atomics
__global__ __launch_bounds__(512) void k_gcnt(const int* __restrict__ batch,
                                              int* __restrict__ gcnt) {
  __shared__ int first[N_GRAPHS + 1];
  int g = threadIdx.x;
  int lo = 0, hi = N_NODES;
  while (lo < hi) {
    int mid = (lo + hi) >> 1;
    if (batch[mid] < g) lo = mid + 1; else hi = mid;
  }
  first[g] = lo;
  if (g == 0) first[N_GRAPHS] = N_NODES;
  __syncthreads();
  gcnt[g] = first[g + 1] - first[g];
}

// ---------------- row_ptr scans (over pad8(deg)) ----------------

__global__ __launch_bounds__(256) void k_scanA(const int* __restrict__ degcnt,
                                               int* __restrict__ blocksum) {
  __shared__ int sh[256];
  int t = threadIdx.x;
  int base = blockIdx.x * 1024;
  int s = 0;
#pragma unroll
  for (int j = 0; j < 4; j++) {
    int idx = base + t * 4 + j;
    if (idx < N_NODES) s += pad8(degcnt[idx]);
  }
  sh[t] = s;
  __syncthreads();
  for (int off = 128; off > 0; off >>= 1) {
    if (t < off) sh[t] += sh[t + off];
    __syncthreads();
  }
  if (t == 0) blocksum[blockIdx.x] = sh[0];
}

__global__ __launch_bounds__(128) void k_scanB(const int* __restrict__ blocksum,
                                               int* __restrict__ blockoff,
                                               int* __restrict__ total_out, int nb) {
  __shared__ int sh[128];
  int t = threadIdx.x;
  int v = (t < nb) ? blocksum[t] : 0;
  sh[t] = v;
  __syncthreads();
  for (int off = 1; off < 128; off <<= 1) {
    int add = (t >= off) ? sh[t - off] : 0;
    __syncthreads();
    sh[t] += add;
    __syncthreads();
  }
  if (t < nb) blockoff[t] = sh[t] - v;   // exclusive
  if (t == nb - 1) total_out[0] = sh[t];
}

__global__ __launch_bounds__(256) void k_scanC(const int* __restrict__ degcnt,
                                               const int* __restrict__ blockoff,
                                               int* __restrict__ row_ptr) {
  __shared__ int sh[256];
  int t = threadIdx.x;
  int base = blockIdx.x * 1024;
  int v[4];
#pragma unroll
  for (int j = 0; j < 4; j++) {
    int idx = base + t * 4 + j;
    v[j] = (idx < N_NODES) ? pad8(degcnt[idx]) : 0;
  }
  int tsum = v[0] + v[1] + v[2] + v[3];
  sh[t] = tsum;
  __syncthreads();
  for (int off = 1; off < 256; off <<= 1) {
    int add = (t >= off) ? sh[t - off] : 0;
    __syncthreads();
    sh[t] += add;
    __syncthreads();
  }
  int p = sh[t] - tsum + blockoff[blockIdx.x];
#pragma unroll
  for (int j = 0; j < 4; j++) {
    int idx = base + t * 4 + j;
    if (idx < N_NODES) row_ptr[idx] = p;
    p += v[j];
  }
}

// ---------------- two-phase binned CSR fill (also produces degcnt) ----------------

__global__ __launch_bounds__(256) void k_binA(const int* __restrict__ dst,
                                              int* __restrict__ cnt) {
  __shared__ int h[NBKT];
  int k = blockIdx.x, t = threadIdx.x;
  for (int i = t; i < NBKT; i += 256) h[i] = 0;
  __syncthreads();
  int e0 = k * EPB;
  int e1 = min(e0 + EPB, N_EDGES);
  for (int e = e0 + t; e < e1; e += 256)
    atomicAdd(&h[(u32)dst[e] / (u32)NPB], 1);
  __syncthreads();
  for (int i = t; i < NBKT; i += 256) cnt[k * NBKT + i] = h[i];
}

// per bucket b: exclusive scan over the ABLK(=1024) block counts, 4 items/thread
__global__ __launch_bounds__(256) void k_binscanA(const int* __restrict__ cnt,
                                                  int* __restrict__ off,
                                                  int* __restrict__ tot) {
  __shared__ int sh[256];
  int b = blockIdx.x, t = threadIdx.x;
  int v[4];
#pragma unroll
  for (int j = 0; j < 4; j++) v[j] = cnt[(t * 4 + j) * NBKT + b];
  int tsum = v[0] + v[1] + v[2] + v[3];
  sh[t] = tsum;
  __syncthreads();
  for (int o = 1; o < 256; o <<= 1) {
    int add = (t >= o) ? sh[t - o] : 0;
    __syncthreads();
    sh[t] += add;
    __syncthreads();
  }
  int p = sh[t] - tsum;
#pragma unroll
  for (int j = 0; j < 4; j++) {
    off[(t * 4 + j) * NBKT + b] = p;
    p += v[j];
  }
  if (t == 255) tot[b] = p;
}

__global__ __launch_bounds__(256) void k_binscanB(const int* __restrict__ tot,
                                                  int* __restrict__ base) {
  __shared__ int sh[256];
  int t = threadIdx.x;
  int v = (t < NBKT) ? tot[t] : 0;
  sh[t] = v;
  __syncthreads();
  for (int o = 1; o < 256; o <<= 1) {
    int add = (t >= o) ? sh[t - o] : 0;
    __syncthreads();
    sh[t] += add;
    __syncthreads();
  }
  if (t < NBKT) base[t] = sh[t] - v;
  if (t == NBKT - 1) base[NBKT] = sh[t];
}

__global__ __launch_bounds__(256) void k_binscat(const int* __restrict__ src,
                                                 const int* __restrict__ dst,
                                                 const int* __restrict__ off,
                                                 const int* __restrict__ base,
                                                 u32* __restrict__ binbuf) {
  __shared__ int posB[NBKT];
  __shared__ int h[NBKT];
  int k = blockIdx.x, t = threadIdx.x;
  for (int i = t; i < NBKT; i += 256) {
    posB[i] = base[i] + off[k * NBKT + i];
    h[i] = 0;
  }
  __syncthreads();
  int e0 = k * EPB;
  int e1 = min(e0 + EPB, N_EDGES);
  for (int e = e0 + t; e < e1; e += 256) {
    u32 d = (u32)dst[e];
    int b = d / (u32)NPB;
    int r = atomicAdd(&h[b], 1);
    binbuf[posB[b] + r] = (u32)src[e] * (u32)NPB + (d - (u32)b * NPB);
  }
}

// degree histogram from binned data: LDS counters only, zero global atomics
__global__ __launch_bounds__(256) void k_bdeg(const u32* __restrict__ binbuf,
                                              const int* __restrict__ base,
                                              int* __restrict__ degcnt) {
  __shared__ int c[NPB];
  int b = blockIdx.x, t = threadIdx.x;
  for (int i = t; i < NPB; i += 256) c[i] = 0;
  __syncthreads();
  int s0 = base[b], s1 = base[b + 1];
  for (int i = s0 + t; i < s1; i += 256) {
    u32 p = binbuf[i];
    u32 s = p / (u32)NPB;
    atomicAdd(&c[p - s * (u32)NPB], 1);
  }
  __syncthreads();
  for (int i = t; i < NPB; i += 256) degcnt[b * NPB + i] = c[i];
}

__global__ __launch_bounds__(256) void k_fillB(const u32* __restrict__ binbuf,
                                               const int* __restrict__ base,
                                               const int* __restrict__ row_ptr,
                                               int* __restrict__ col) {
  __shared__ int rp[NPB + 1];
  __shared__ int cur[NPB];
  int b = blockIdx.x, t = threadIdx.x;
  for (int i = t; i < NPB + 1; i += 256) rp[i] = row_ptr[b * NPB + i];
  for (int i = t; i < NPB; i += 256) cur[i] = 0;
  __syncthreads();
  int s0 = base[b], s1 = base[b + 1];
  for (int i = s0 + t; i < s1; i += 256) {
    u32 p = binbuf[i];
    u32 s = p / (u32)NPB;
    int ld = p - s * (u32)NPB;
    int pos = atomicAdd(&cur[ld], 1);
    col[rp[ld] + pos] = (int)s;
  }
  __syncthreads();
  for (int ld = t; ld < NPB; ld += 256) {
    int bs = rp[ld], len = rp[ld + 1] - bs, c = cur[ld];
    for (int j = c; j < len; j++) col[bs + j] = ZROW;
  }
}

// ---------------- GEMMs via MFMA 16x16x32 f16 (W in register B-frags) ----------------
// A layout: lane l holds A[m = l&15][k = (l>>4)*8 + j], j=0..7
// B layout: lane l holds B[k = (l>>4)*8 + j][n = l&15]
// C/D layout: col = l&15, row = (l>>4)*4 + reg   [m89-verified]

__global__ __launch_bounds__(256) void k_gemm1(const float* __restrict__ x,
                                               const float* __restrict__ W1,
                                               const float* __restrict__ dis,
                                               u16* __restrict__ hs1) {
  int wid = (blockIdx.x * 256 + threadIdx.x) >> 6;   // wave id = 16-row tile
  if (wid >= NTILE) return;
  int l = threadIdx.x & 63;
  int m = l & 15, q = l >> 4;
  f16x8 B[4][2];
#pragma unroll
  for (int s = 0; s < 4; ++s)
#pragma unroll
    for (int h = 0; h < 2; ++h)
#pragma unroll
      for (int j = 0; j < 8; ++j)
        B[s][h][j] = (f16)W1[(s * 32 + q * 8 + j) * EMB + h * 16 + m];
  int row = wid * 16 + m;
  const float* xr = x + (size_t)row * FEAT + q * 8;
  f32x4 acc0 = {0.f, 0.f, 0.f, 0.f}, acc1 = {0.f, 0.f, 0.f, 0.f};
#pragma unroll
  for (int s = 0; s < 4; ++s) {
    f32x4 xa = __builtin_nontemporal_load((const f32x4*)(xr + s * 32));
    f32x4 xb = __builtin_nontemporal_load((const f32x4*)(xr + s * 32 + 4));
    f16x8 A;
    A[0] = (f16)xa.x; A[1] = (f16)xa.y; A[2] = (f16)xa.z; A[3] = (f16)xa.w;
    A[4] = (f16)xb.x; A[5] = (f16)xb.y; A[6] = (f16)xb.z; A[7] = (f16)xb.w;
    acc0 = __builtin_amdgcn_mfma_f32_16x16x32_f16(A, B[s][0], acc0, 0, 0, 0);
    acc1 = __builtin_amdgcn_mfma_f32_16x16x32_f16(A, B[s][1], acc1, 0, 0, 0);
  }
  f32x4 dq = *(const f32x4*)(dis + wid * 16 + q * 4);
  u16* o = hs1 + (size_t)(wid * 16) * EMB;
#pragma unroll
  for (int i = 0; i < 4; ++i) {
    int r = q * 4 + i;
    float dv = (i == 0) ? dq.x : (i == 1) ? dq.y : (i == 2) ? dq.z : dq.w;
    o[(size_t)r * EMB + m]      = __half_as_ushort(__float2half_rn(acc0[i] * dv));
    o[(size_t)r * EMB + 16 + m] = __half_as_ushort(__float2half_rn(acc1[i] * dv));
  }
}

__global__ __launch_bounds__(256) void k_gemm2(const u16* __restrict__ in1,
                                               const float* __restrict__ W2,
                                               const float* __restrict__ dis,
                                               u16* __restrict__ hs2) {
  int wid = (blockIdx.x * 256 + threadIdx.x) >> 6;
  if (wid >= NTILE) return;
  int l = threadIdx.x & 63;
  int m = l & 15, q = l >> 4;
  f16x8 B[2];
#pragma unroll
  for (int h = 0; h < 2; ++h)
#pragma unroll
    for (int j = 0; j < 8; ++j)
      B[h][j] = (f16)W2[(q * 8 + j) * EMB + h * 16 + m];
  int row = wid * 16 + m;
  f16x8 A = *(const f16x8*)(in1 + (size_t)row * EMB + q * 8);
  f32x4 acc0 = {0.f, 0.f, 0.f, 0.f}, acc1 = {0.f, 0.f, 0.f, 0.f};
  acc0 = __builtin_amdgcn_mfma_f32_16x16x32_f16(A, B[0], acc0, 0, 0, 0);
  acc1 = __builtin_amdgcn_mfma_f32_16x16x32_f16(A, B[1], acc1, 0, 0, 0);
  f32x4 dq = *(const f32x4*)(dis + wid * 16 + q * 4);
  u16* o = hs2 + (size_t)(wid * 16) * EMB;
#pragma unroll
  for (int i = 0; i < 4; ++i) {
    int r = q * 4 + i;
    float dv = (i == 0) ? dq.x : (i == 1) ? dq.y : (i == 2) ? dq.z : dq.w;
    o[(size_t)r * EMB + m]      = __half_as_ushort(__float2half_rn(acc0[i] * dv));
    o[(size_t)r * EMB + 16 + m] = __half_as_ushort(__float2half_rn(acc1[i] * dv));
  }
}

// ---------------- Aggregation: wave-per-node, 8 rows per gather instruction ----------------

__device__ __forceinline__ float4 agg_row_wide(const u16* __restrict__ hs,
                                               const int* __restrict__ row_ptr,
                                               const int* __restrict__ col,
                                               int n, int g, int sub) {
  const u16x4* hs4 = (const u16x4*)hs;
  int e0 = row_ptr[n], e1 = row_ptr[n + 1];   // multiple of 8 apart
  int nch = (e1 - e0) >> 3;
  int ec = e0 + g;
  float4 acc = make_float4(0.f, 0.f, 0.f, 0.f);
  int s0 = (nch > 0) ? __builtin_nontemporal_load(&col[ec]) : ZROW;
  int s1 = (nch > 1) ? __builtin_nontemporal_load(&col[ec + 8]) : ZROW;
  int i = 0;
  for (; i + 2 <= nch; i += 2) {
    u16x4 va = hs4[(size_t)s0 * 8 + sub];
    u16x4 vb = hs4[(size_t)s1 * 8 + sub];
    int t0 = (i + 2 < nch) ? __builtin_nontemporal_load(&col[ec + (i + 2) * 8]) : ZROW;
    int t1 = (i + 3 < nch) ? __builtin_nontemporal_load(&col[ec + (i + 3) * 8]) : ZROW;
    float4 fa = h4_to_f4(va);
    float4 fb = h4_to_f4(vb);
    acc.x += fa.x + fb.x;
    acc.y += fa.y + fb.y;
    acc.z += fa.z + fb.z;
    acc.w += fa.w + fb.w;
    s0 = t0;
    s1 = t1;
  }
  if (i < nch) {
    float4 fa = h4_to_f4(hs4[(size_t)s0 * 8 + sub]);
    acc.x += fa.x; acc.y += fa.y; acc.z += fa.z; acc.w += fa.w;
  }
#pragma unroll
  for (int mm = 8; mm < 64; mm <<= 1) {
    acc.x += __shfl_xor(acc.x, mm);
    acc.y += __shfl_xor(acc.y, mm);
    acc.z += __shfl_xor(acc.z, mm);
    acc.w += __shfl_xor(acc.w, mm);
  }
  // self-loop (hs already dis-scaled); added post-reduction => counted once
  float4 sf = h4_to_f4(hs4[(size_t)n * 8 + sub]);
  acc.x += sf.x; acc.y += sf.y; acc.z += sf.z; acc.w += sf.w;
  return acc;
}

__global__ __launch_bounds__(256) void k_agg1(const u16* __restrict__ hs,
                                              const int* __restrict__ row_ptr,
                                              const int* __restrict__ col,
                                              const float* __restrict__ dis,
                                              const float* __restrict__ b,
                                              u16* __restrict__ out) {
  int t = threadIdx.x;
  int n = blockIdx.x * 4 + (t >> 6);
  int l = t & 63;
  int g = (l >> 3), sub = l & 7;
  float4 acc = agg_row_wide(hs, row_ptr, col, n, g, sub);
  if (g == 0) {
    float d = dis[n];
    float4 bq = ((const float4*)b)[sub];
    float4 o;
    o.x = fmaxf(fmaf(acc.x, d, bq.x), 0.f);
    o.y = fmaxf(fmaf(acc.y, d, bq.y), 0.f);
    o.z = fmaxf(fmaf(acc.z, d, bq.z), 0.f);
    o.w = fmaxf(fmaf(acc.w, d, bq.w), 0.f);
    ((u16x4*)(out + (size_t)n * EMB))[sub] = f4_to_h4(o);
  }
}

// pooling tail: privatized 64-copy accumulator kills same-line atomic contention
__global__ __launch_bounds__(256) void k_agg2pool(const u16* __restrict__ hs,
                                                  const int* __restrict__ row_ptr,
                                                  const int* __restrict__ col,
                                                  const float* __restrict__ dis,
                                                  const float* __restrict__ b2,
                                                  const float* __restrict__ Wo,
                                                  const int* __restrict__ batch,
                                                  float* __restrict__ gaccP) {
  int t = threadIdx.x;
  int n = blockIdx.x * 4 + (t >> 6);
  int l = t & 63;
  int g = (l >> 3), sub = l & 7;
  float4 acc = agg_row_wide(hs, row_ptr, col, n, g, sub);
  float d = dis[n];
  float4 bq = ((const float4*)b2)[sub];
  float4 wq = ((const float4*)Wo)[sub];
  float p = fmaxf(fmaf(acc.x, d, bq.x), 0.f) * wq.x
          + fmaxf(fmaf(acc.y, d, bq.y), 0.f) * wq.y
          + fmaxf(fmaf(acc.z, d, bq.z), 0.f) * wq.z
          + fmaxf(fmaf(acc.w, d, bq.w), 0.f) * wq.w;
  p += __shfl_xor(p, 1);
  p += __shfl_xor(p, 2);
  p += __shfl_xor(p, 4);
  if (l == 0) {
    int copy = blockIdx.x & (NCOPY - 1);
    atomicAdd(&gaccP[copy * N_GRAPHS + batch[n]], p);
  }
}

__global__ __launch_bounds__(256) void k_finalize(const float* __restrict__ gaccP,
                                                  const int* __restrict__ gcnt,
                                                  const float* __restrict__ bo,
                                                  float* __restrict__ out) {
  int g = blockIdx.x * 256 + threadIdx.x;
  if (g < N_GRAPHS) {
    float s = 0.f;
#pragma unroll 8
    for (int c = 0; c < NCOPY; ++c) s += gaccP[c * N_GRAPHS + g];
    out[g] = s / fmaxf((float)gcnt[g], 1.0f) + bo[0];
  }
}

// ---------------- launch ----------------

extern "C" void kernel_launch(void* const* d_in, const int* in_sizes, int n_in,
                              void* d_out, int out_size, void* d_ws, size_t ws_size,
                              hipStream_t stream) {
  const float* x     = (const float*)d_in[0];
  const int*   ei    = (const int*)d_in[1];   // [2, E]: src then dst
  const int*   batch = (const int*)d_in[2];
  const float* W1    = (const float*)d_in[3];
  const float* b1    = (const float*)d_in[4];
  const float* W2    = (const float*)d_in[5];
  const float* b2    = (const float*)d_in[6];
  const float* Wo    = (const float*)d_in[7];
  const float* bo    = (const float*)d_in[8];
  float* out = (float*)d_out;

  const int* src = ei;
  const int* dst = ei + N_EDGES;

  char* w = (char*)d_ws;
  float* gaccP   = (float*)w;  w += (size_t)NCOPY * N_GRAPHS * 4;   // zeroed
  size_t zero_bytes = (size_t)(w - (char*)d_ws);
  int*   degcnt  = (int*)w;    w += (size_t)N_NODES * 4;            // written by k_bdeg
  int*   gcnt    = (int*)w;    w += (size_t)N_GRAPHS * 4;
  int*   row_ptr = (int*)w;    w += (size_t)(N_NODES + 4) * 4;
  int*   blocksum= (int*)w;    w += 128 * 4;
  int*   blockoff= (int*)w;    w += 128 * 4;
  int*   cnt     = (int*)w;    w += (size_t)ABLK * NBKT * 4;        // 1.0 MB
  int*   boff    = (int*)w;    w += (size_t)ABLK * NBKT * 4;        // 1.0 MB
  int*   btot    = (int*)w;    w += (size_t)(NBKT + 8) * 4;
  int*   bbase   = (int*)w;    w += (size_t)(NBKT + 8) * 4;
  int*   col     = (int*)w;    w += (size_t)PADCAP * 4;
  float* dis     = (float*)w;  w += (size_t)N_NODES * 4;
  u16*   hs1     = (u16*)w;    w += (size_t)(N_NODES + 1) * EMB * 2;  // +1 zero row
  u16*   out1    = (u16*)w;    w += (size_t)N_NODES * EMB * 2;        // 6.4 MB
  u32*   binbuf  = (u32*)out1;  // alias: binbuf dead before agg1 writes out1
  u16*   hs2     = hs1;         // hs1 dead after agg1; zero row persists

  const int NB = (N_NODES + 255) / 256;    // 391
  const int SB = (N_NODES + 1023) / 1024;  // 98
  const int GB = (NTILE * 64 + 255) / 256; // 1563 MFMA blocks
  const int AB = N_NODES / 4;              // 25000 wave-per-node blocks

  (void)hipMemsetAsync(d_ws, 0, zero_bytes, stream);

  // bin pipeline (produces binbuf + degree histogram)
  k_binA<<<ABLK, 256, 0, stream>>>(dst, cnt);
  k_binscanA<<<NBKT, 256, 0, stream>>>(cnt, boff, btot);
  k_binscanB<<<1, 256, 0, stream>>>(btot, bbase);
  k_binscat<<<ABLK, 256, 0, stream>>>(src, dst, boff, bbase, binbuf);
  k_bdeg<<<NBKT, 256, 0, stream>>>(binbuf, bbase, degcnt);

  k_node_init<<<NB, 256, 0, stream>>>(degcnt, dis, hs1);
  k_gcnt<<<1, 512, 0, stream>>>(batch, gcnt);
  k_scanA<<<SB, 256, 0, stream>>>(degcnt, blocksum);
  k_scanB<<<1, 128, 0, stream>>>(blocksum, blockoff, row_ptr + N_NODES, SB);
  k_scanC<<<SB, 256, 0, stream>>>(degcnt, blockoff, row_ptr);
  k_fillB<<<NBKT, 256, 0, stream>>>(binbuf, bbase, row_ptr, col);

  k_gemm1<<<GB, 256, 0, stream>>>(x, W1, dis, hs1);
  k_agg1<<<AB, 256, 0, stream>>>(hs1, row_ptr, col, dis, b1, out1);
  k_gemm2<<<GB, 256, 0, stream>>>(out1, W2, dis, hs2);
  k_agg2pool<<<AB, 256, 0, stream>>>(hs2, row_ptr, col, dis, b2, Wo, batch, gaccP);
  k_finalize<<<2, 256, 0, stream>>>(gaccP, gcnt, bo, out);
}

// Round 13
// 263.474 us; speedup vs baseline: 3.1966x; 1.0553x over previous
//
#include <hip/hip_runtime.h>
#include <hip/hip_fp16.h>

#define N_NODES 100000
#define N_EDGES 1600000
#define N_GRAPHS 512
#define FEAT 128
#define EMB 32
#define ZROW N_NODES                        // dedicated zero row for padding
#define PADCAP (N_EDGES + 8 * N_NODES)      // pad8 worst-case col slots
#define NCOPY 64                            // privatized pool accumulator copies
#define NBKT 250                            // dst buckets (400 nodes each)
#define NPB 400                             // nodes per bucket
#define ABLK 1024                           // bin phase blocks
#define EPB 1563                            // ceil(N_EDGES / ABLK)
#define NTILE (N_NODES / 16)                // 6250 MFMA row tiles

typedef unsigned short u16;
typedef unsigned int u32;
typedef _Float16 f16;
typedef float f32x4 __attribute__((ext_vector_type(4)));
typedef unsigned short u16x4 __attribute__((ext_vector_type(4)));
typedef f16 f16x8 __attribute__((ext_vector_type(8)));

__device__ __forceinline__ int pad8(int d) { return (d + 7) & ~7; }

__device__ __forceinline__ float4 h4_to_f4(u16x4 v) {
  union { unsigned int u; __half2 h; } a, b;
  a.u = (unsigned int)v.x | ((unsigned int)v.y << 16);
  b.u = (unsigned int)v.z | ((unsigned int)v.w << 16);
  float2 f0 = __half22float2(a.h);
  float2 f1 = __half22float2(b.h);
  return make_float4(f0.x, f0.y, f1.x, f1.y);
}

__device__ __forceinline__ u16x4 f4_to_h4(float4 f) {
  union { unsigned int u; __half2 h; } a, b;
  a.h = __float22half2_rn(make_float2(f.x, f.y));
  b.h = __float22half2_rn(make_float2(f.z, f.w));
  u16x4 r;
  r.x = (u16)(a.u & 0xffff); r.y = (u16)(a.u >> 16);
  r.z = (u16)(b.u & 0xffff); r.w = (u16)(b.u >> 16);
  return r;
}

// ---------------- misc ----------------

__global__ __launch_bounds__(256) void k_node_init(const int* __restrict__ degcnt,
                                                   float* __restrict__ dis,
                                                   u16* __restrict__ hs1) {
  int i = blockIdx.x * 256 + threadIdx.x;
  if (i < N_NODES) dis[i] = rsqrtf((float)degcnt[i] + 1.0f);
  if (i < EMB) hs1[(size_t)ZROW * EMB + i] = 0;
}

__global__ __launch_bounds__(512) void k_gcnt(const int* __restrict__ batch,
                                              int* __restrict__ gcnt) {
  __shared__ int first[N_GRAPHS + 1];
  int g = threadIdx.x;
  int lo = 0, hi = N_NODES;
  while (lo < hi) {
    int mid = (lo + hi) >> 1;
    if (batch[mid] < g) lo = mid + 1; else hi = mid;
  }
  first[g] = lo;
  if (g == 0) first[N_GRAPHS] = N_NODES;
  __syncthreads();
  gcnt[g] = first[g + 1] - first[g];
}

// ---------------- row_ptr scans (over pad8(deg)) ----------------

__global__ __launch_bounds__(256) void k_scanA(const int* __restrict__ degcnt,
                                               int* __restrict__ blocksum) {
  __shared__ int sh[256];
  int t = threadIdx.x;
  int base = blockIdx.x * 1024;
  int s = 0;
#pragma unroll
  for (int j = 0; j < 4; j++) {
    int idx = base + t * 4 + j;
    if (idx < N_NODES) s += pad8(degcnt[idx]);
  }
  sh[t] = s;
  __syncthreads();
  for (int off = 128; off > 0; off >>= 1) {
    if (t < off) sh[t] += sh[t + off];
    __syncthreads();
  }
  if (t == 0) blocksum[blockIdx.x] = sh[0];
}

__global__ __launch_bounds__(128) void k_scanB(const int* __restrict__ blocksum,
                                               int* __restrict__ blockoff,
                                               int* __restrict__ total_out, int nb) {
  __shared__ int sh[128];
  int t = threadIdx.x;
  int v = (t < nb) ? blocksum[t] : 0;
  sh[t] = v;
  __syncthreads();
  for (int off = 1; off < 128; off <<= 1) {
    int add = (t >= off) ? sh[t - off] : 0;
    __syncthreads();
    sh[t] += add;
    __syncthreads();
  }
  if (t < nb) blockoff[t] = sh[t] - v;   // exclusive
  if (t == nb - 1) total_out[0] = sh[t];
}

__global__ __launch_bounds__(256) void k_scanC(const int* __restrict__ degcnt,
                                               const int* __restrict__ blockoff,
                                               int* __restrict__ row_ptr) {
  __shared__ int sh[256];
  int t = threadIdx.x;
  int base = blockIdx.x * 1024;
  int v[4];
#pragma unroll
  for (int j = 0; j < 4; j++) {
    int idx = base + t * 4 + j;
    v[j] = (idx < N_NODES) ? pad8(degcnt[idx]) : 0;
  }
  int tsum = v[0] + v[1] + v[2] + v[3];
  sh[t] = tsum;
  __syncthreads();
  for (int off = 1; off < 256; off <<= 1) {
    int add = (t >= off) ? sh[t - off] : 0;
    __syncthreads();
    sh[t] += add;
    __syncthreads();
  }
  int p = sh[t] - tsum + blockoff[blockIdx.x];
#pragma unroll
  for (int j = 0; j < 4; j++) {
    int idx = base + t * 4 + j;
    if (idx < N_NODES) row_ptr[idx] = p;
    p += v[j];
  }
}

// ---------------- two-phase binned CSR fill (also produces degcnt) ----------------

__global__ __launch_bounds__(256) void k_binA(const int* __restrict__ dst,
                                              int* __restrict__ cnt) {
  __shared__ int h[NBKT];
  int k = blockIdx.x, t = threadIdx.x;
  for (int i = t; i < NBKT; i += 256) h[i] = 0;
  __syncthreads();
  int e0 = k * EPB;
  int e1 = min(e0 + EPB, N_EDGES);
  for (int e = e0 + t; e < e1; e += 256)
    atomicAdd(&h[(u32)dst[e] / (u32)NPB], 1);
  __syncthreads();
  for (int i = t; i < NBKT; i += 256) cnt[k * NBKT + i] = h[i];
}

__global__ __launch_bounds__(256) void k_binscanA(const int* __restrict__ cnt,
                                                  int* __restrict__ off,
                                                  int* __restrict__ tot) {
  __shared__ int sh[256];
  int b = blockIdx.x, t = threadIdx.x;
  int v[4];
#pragma unroll
  for (int j = 0; j < 4; j++) v[j] = cnt[(t * 4 + j) * NBKT + b];
  int tsum = v[0] + v[1] + v[2] + v[3];
  sh[t] = tsum;
  __syncthreads();
  for (int o = 1; o < 256; o <<= 1) {
    int add = (t >= o) ? sh[t - o] : 0;
    __syncthreads();
    sh[t] += add;
    __syncthreads();
  }
  int p = sh[t] - tsum;
#pragma unroll
  for (int j = 0; j < 4; j++) {
    off[(t * 4 + j) * NBKT + b] = p;
    p += v[j];
  }
  if (t == 255) tot[b] = p;
}

__global__ __launch_bounds__(256) void k_binscanB(const int* __restrict__ tot,
                                                  int* __restrict__ base) {
  __shared__ int sh[256];
  int t = threadIdx.x;
  int v = (t < NBKT) ? tot[t] : 0;
  sh[t] = v;
  __syncthreads();
  for (int o = 1; o < 256; o <<= 1) {
    int add = (t >= o) ? sh[t - o] : 0;
    __syncthreads();
    sh[t] += add;
    __syncthreads();
  }
  if (t < NBKT) base[t] = sh[t] - v;
  if (t == NBKT - 1) base[NBKT] = sh[t];
}

__global__ __launch_bounds__(256) void k_binscat(const int* __restrict__ src,
                                                 const int* __restrict__ dst,
                                                 const int* __restrict__ off,
                                                 const int* __restrict__ base,
                                                 u32* __restrict__ binbuf) {
  __shared__ int posB[NBKT];
  __shared__ int h[NBKT];
  int k = blockIdx.x, t = threadIdx.x;
  for (int i = t; i < NBKT; i += 256) {
    posB[i] = base[i] + off[k * NBKT + i];
    h[i] = 0;
  }
  __syncthreads();
  int e0 = k * EPB;
  int e1 = min(e0 + EPB, N_EDGES);
  for (int e = e0 + t; e < e1; e += 256) {
    u32 d = (u32)dst[e];
    int b = d / (u32)NPB;
    int r = atomicAdd(&h[b], 1);
    binbuf[posB[b] + r] = (u32)src[e] * (u32)NPB + (d - (u32)b * NPB);
  }
}

__global__ __launch_bounds__(256) void k_bdeg(const u32* __restrict__ binbuf,
                                              const int* __restrict__ base,
                                              int* __restrict__ degcnt) {
  __shared__ int c[NPB];
  int b = blockIdx.x, t = threadIdx.x;
  for (int i = t; i < NPB; i += 256) c[i] = 0;
  __syncthreads();
  int s0 = base[b], s1 = base[b + 1];
  for (int i = s0 + t; i < s1; i += 256) {
    u32 p = binbuf[i];
    u32 s = p / (u32)NPB;
    atomicAdd(&c[p - s * (u32)NPB], 1);
  }
  __syncthreads();
  for (int i = t; i < NPB; i += 256) degcnt[b * NPB + i] = c[i];
}

__global__ __launch_bounds__(256) void k_fillB(const u32* __restrict__ binbuf,
                                               const int* __restrict__ base,
                                               const int* __restrict__ row_ptr,
                                               int* __restrict__ col) {
  __shared__ int rp[NPB + 1];
  __shared__ int cur[NPB];
  int b = blockIdx.x, t = threadIdx.x;
  for (int i = t; i < NPB + 1; i += 256) rp[i] = row_ptr[b * NPB + i];
  for (int i = t; i < NPB; i += 256) cur[i] = 0;
  __syncthreads();
  int s0 = base[b], s1 = base[b + 1];
  for (int i = s0 + t; i < s1; i += 256) {
    u32 p = binbuf[i];
    u32 s = p / (u32)NPB;
    int ld = p - s * (u32)NPB;
    int pos = atomicAdd(&cur[ld], 1);
    col[rp[ld] + pos] = (int)s;
  }
  __syncthreads();
  for (int ld = t; ld < NPB; ld += 256) {
    int bs = rp[ld], len = rp[ld + 1] - bs, c = cur[ld];
    for (int j = c; j < len; j++) col[bs + j] = ZROW;
  }
}

// ---------------- GEMMs via MFMA 16x16x32 f16 (W in register B-frags) ----------------

__global__ __launch_bounds__(256) void k_gemm1(const float* __restrict__ x,
                                               const float* __restrict__ W1,
                                               const float* __restrict__ dis,
                                               u16* __restrict__ hs1) {
  int wid = (blockIdx.x * 256 + threadIdx.x) >> 6;   // wave id = 16-row tile
  if (wid >= NTILE) return;
  int l = threadIdx.x & 63;
  int m = l & 15, q = l >> 4;
  f16x8 B[4][2];
#pragma unroll
  for (int s = 0; s < 4; ++s)
#pragma unroll
    for (int h = 0; h < 2; ++h)
#pragma unroll
      for (int j = 0; j < 8; ++j)
        B[s][h][j] = (f16)W1[(s * 32 + q * 8 + j) * EMB + h * 16 + m];
  int row = wid * 16 + m;
  const float* xr = x + (size_t)row * FEAT + q * 8;
  f32x4 acc0 = {0.f, 0.f, 0.f, 0.f}, acc1 = {0.f, 0.f, 0.f, 0.f};
#pragma unroll
  for (int s = 0; s < 4; ++s) {
    f32x4 xa = __builtin_nontemporal_load((const f32x4*)(xr + s * 32));
    f32x4 xb = __builtin_nontemporal_load((const f32x4*)(xr + s * 32 + 4));
    f16x8 A;
    A[0] = (f16)xa.x; A[1] = (f16)xa.y; A[2] = (f16)xa.z; A[3] = (f16)xa.w;
    A[4] = (f16)xb.x; A[5] = (f16)xb.y; A[6] = (f16)xb.z; A[7] = (f16)xb.w;
    acc0 = __builtin_amdgcn_mfma_f32_16x16x32_f16(A, B[s][0], acc0, 0, 0, 0);
    acc1 = __builtin_amdgcn_mfma_f32_16x16x32_f16(A, B[s][1], acc1, 0, 0, 0);
  }
  f32x4 dq = *(const f32x4*)(dis + wid * 16 + q * 4);
  u16* o = hs1 + (size_t)(wid * 16) * EMB;
#pragma unroll
  for (int i = 0; i < 4; ++i) {
    int r = q * 4 + i;
    float dv = (i == 0) ? dq.x : (i == 1) ? dq.y : (i == 2) ? dq.z : dq.w;
    o[(size_t)r * EMB + m]      = __half_as_ushort(__float2half_rn(acc0[i] * dv));
    o[(size_t)r * EMB + 16 + m] = __half_as_ushort(__float2half_rn(acc1[i] * dv));
  }
}

__global__ __launch_bounds__(256) void k_gemm2(const u16* __restrict__ in1,
                                               const float* __restrict__ W2,
                                               const float* __restrict__ dis,
                                               u16* __restrict__ hs2) {
  int wid = (blockIdx.x * 256 + threadIdx.x) >> 6;
  if (wid >= NTILE) return;
  int l = threadIdx.x & 63;
  int m = l & 15, q = l >> 4;
  f16x8 B[2];
#pragma unroll
  for (int h = 0; h < 2; ++h)
#pragma unroll
    for (int j = 0; j < 8; ++j)
      B[h][j] = (f16)W2[(q * 8 + j) * EMB + h * 16 + m];
  int row = wid * 16 + m;
  f16x8 A = *(const f16x8*)(in1 + (size_t)row * EMB + q * 8);
  f32x4 acc0 = {0.f, 0.f, 0.f, 0.f}, acc1 = {0.f, 0.f, 0.f, 0.f};
  acc0 = __builtin_amdgcn_mfma_f32_16x16x32_f16(A, B[0], acc0, 0, 0, 0);
  acc1 = __builtin_amdgcn_mfma_f32_16x16x32_f16(A, B[1], acc1, 0, 0, 0);
  f32x4 dq = *(const f32x4*)(dis + wid * 16 + q * 4);
  u16* o = hs2 + (size_t)(wid * 16) * EMB;
#pragma unroll
  for (int i = 0; i < 4; ++i) {
    int r = q * 4 + i;
    float dv = (i == 0) ? dq.x : (i == 1) ? dq.y : (i == 2) ? dq.z : dq.w;
    o[(size_t)r * EMB + m]      = __half_as_ushort(__float2half_rn(acc0[i] * dv));
    o[(size_t)r * EMB + 16 + m] = __half_as_ushort(__float2half_rn(acc1[i] * dv));
  }
}

// ---------------- Aggregation: TWO nodes per wave, 4 gather streams in flight ----------------
// R12 PMC: agg at 1.8 TB/s L2-miss BW, VALU 44%, occ 66% -> latency*concurrency
// bound (~22 lines/CU needed at ~500cyc; 21 waves x ~1-2 outstanding). Doubling
// per-wave MLP (2 nodes, 4 interleaved gathers + 4 col prefetches) attacks that.

__device__ __forceinline__ void agg_two(const u16* __restrict__ hs,
                                        const int* __restrict__ row_ptr,
                                        const int* __restrict__ col,
                                        int n0, int n1, int g, int sub,
                                        float4& R0, float4& R1) {
  const u16x4* hs4 = (const u16x4*)hs;
  int a0 = row_ptr[n0], a1 = row_ptr[n0 + 1];
  int b0 = row_ptr[n1], b1 = row_ptr[n1 + 1];
  int na = (a1 - a0) >> 3, nb = (b1 - b0) >> 3;   // 8-slot chunks per node
  int nch = max(na, nb);
  int eca = a0 + g, ecb = b0 + g;
  float4 A = make_float4(0.f, 0.f, 0.f, 0.f);
  float4 B = make_float4(0.f, 0.f, 0.f, 0.f);
  int sa0 = (0 < na) ? __builtin_nontemporal_load(&col[eca])     : ZROW;
  int sa1 = (1 < na) ? __builtin_nontemporal_load(&col[eca + 8]) : ZROW;
  int sb0 = (0 < nb) ? __builtin_nontemporal_load(&col[ecb])     : ZROW;
  int sb1 = (1 < nb) ? __builtin_nontemporal_load(&col[ecb + 8]) : ZROW;
  for (int i = 0; i < nch; i += 2) {
    u16x4 va0 = hs4[(size_t)sa0 * 8 + sub];
    u16x4 va1 = hs4[(size_t)sa1 * 8 + sub];
    u16x4 vb0 = hs4[(size_t)sb0 * 8 + sub];
    u16x4 vb1 = hs4[(size_t)sb1 * 8 + sub];
    int ta0 = (i + 2 < na) ? __builtin_nontemporal_load(&col[eca + (i + 2) * 8]) : ZROW;
    int ta1 = (i + 3 < na) ? __builtin_nontemporal_load(&col[eca + (i + 3) * 8]) : ZROW;
    int tb0 = (i + 2 < nb) ? __builtin_nontemporal_load(&col[ecb + (i + 2) * 8]) : ZROW;
    int tb1 = (i + 3 < nb) ? __builtin_nontemporal_load(&col[ecb + (i + 3) * 8]) : ZROW;
    float4 fa0 = h4_to_f4(va0), fa1 = h4_to_f4(va1);
    float4 fb0 = h4_to_f4(vb0), fb1 = h4_to_f4(vb1);
    A.x += fa0.x + fa1.x; A.y += fa0.y + fa1.y;
    A.z += fa0.z + fa1.z; A.w += fa0.w + fa1.w;
    B.x += fb0.x + fb1.x; B.y += fb0.y + fb1.y;
    B.z += fb0.z + fb1.z; B.w += fb0.w + fb1.w;
    sa0 = ta0; sa1 = ta1; sb0 = tb0; sb1 = tb1;
  }
#pragma unroll
  for (int mm = 8; mm < 64; mm <<= 1) {
    A.x += __shfl_xor(A.x, mm); A.y += __shfl_xor(A.y, mm);
    A.z += __shfl_xor(A.z, mm); A.w += __shfl_xor(A.w, mm);
    B.x += __shfl_xor(B.x, mm); B.y += __shfl_xor(B.y, mm);
    B.z += __shfl_xor(B.z, mm); B.w += __shfl_xor(B.w, mm);
  }
  float4 s0 = h4_to_f4(hs4[(size_t)n0 * 8 + sub]);
  float4 s1 = h4_to_f4(hs4[(size_t)n1 * 8 + sub]);
  A.x += s0.x; A.y += s0.y; A.z += s0.z; A.w += s0.w;
  B.x += s1.x; B.y += s1.y; B.z += s1.z; B.w += s1.w;
  R0 = A; R1 = B;
}

__device__ __forceinline__ float4 relu_row(float4 acc, float d, float4 bq) {
  float4 o;
  o.x = fmaxf(fmaf(acc.x, d, bq.x), 0.f);
  o.y = fmaxf(fmaf(acc.y, d, bq.y), 0.f);
  o.z = fmaxf(fmaf(acc.z, d, bq.z), 0.f);
  o.w = fmaxf(fmaf(acc.w, d, bq.w), 0.f);
  return o;
}

// grid = N_NODES/8 blocks; wave w handles nodes base+2w, base+2w+1
__global__ __launch_bounds__(256) void k_agg1(const u16* __restrict__ hs,
                                              const int* __restrict__ row_ptr,
                                              const int* __restrict__ col,
                                              const float* __restrict__ dis,
                                              const float* __restrict__ b,
                                              u16* __restrict__ out) {
  int t = threadIdx.x;
  int wv = t >> 6, l = t & 63;
  int n0 = blockIdx.x * 8 + wv * 2, n1 = n0 + 1;
  int g = (l >> 3), sub = l & 7;
  float4 A, B;
  agg_two(hs, row_ptr, col, n0, n1, g, sub, A, B);
  if (g == 0) {
    float4 bq = ((const float4*)b)[sub];
    float4 o0 = relu_row(A, dis[n0], bq);
    float4 o1 = relu_row(B, dis[n1], bq);
    ((u16x4*)(out + (size_t)n0 * EMB))[sub] = f4_to_h4(o0);
    ((u16x4*)(out + (size_t)n1 * EMB))[sub] = f4_to_h4(o1);
  }
}

__global__ __launch_bounds__(256) void k_agg2pool(const u16* __restrict__ hs,
                                                  const int* __restrict__ row_ptr,
                                                  const int* __restrict__ col,
                                                  const float* __restrict__ dis,
                                                  const float* __restrict__ b2,
                                                  const float* __restrict__ Wo,
                                                  const int* __restrict__ batch,
                                                  float* __restrict__ gaccP) {
  int t = threadIdx.x;
  int wv = t >> 6, l = t & 63;
  int n0 = blockIdx.x * 8 + wv * 2, n1 = n0 + 1;
  int g = (l >> 3), sub = l & 7;
  float4 A, B;
  agg_two(hs, row_ptr, col, n0, n1, g, sub, A, B);
  float4 bq = ((const float4*)b2)[sub];
  float4 wq = ((const float4*)Wo)[sub];
  float4 o0 = relu_row(A, dis[n0], bq);
  float4 o1 = relu_row(B, dis[n1], bq);
  float p0 = o0.x * wq.x + o0.y * wq.y + o0.z * wq.z + o0.w * wq.w;
  float p1 = o1.x * wq.x + o1.y * wq.y + o1.z * wq.z + o1.w * wq.w;
  p0 += __shfl_xor(p0, 1); p1 += __shfl_xor(p1, 1);
  p0 += __shfl_xor(p0, 2); p1 += __shfl_xor(p1, 2);
  p0 += __shfl_xor(p0, 4); p1 += __shfl_xor(p1, 4);
  int copy = blockIdx.x & (NCOPY - 1);
  if (l == 0) atomicAdd(&gaccP[copy * N_GRAPHS + batch[n0]], p0);
  if (l == 8) atomicAdd(&gaccP[copy * N_GRAPHS + batch[n1]], p1);
}

__global__ __launch_bounds__(256) void k_finalize(const float* __restrict__ gaccP,
                                                  const int* __restrict__ gcnt,
                                                  const float* __restrict__ bo,
                                                  float* __restrict__ out) {
  int g = blockIdx.x * 256 + threadIdx.x;
  if (g < N_GRAPHS) {
    float s = 0.f;
#pragma unroll 8
    for (int c = 0; c < NCOPY; ++c) s += gaccP[c * N_GRAPHS + g];
    out[g] = s / fmaxf((float)gcnt[g], 1.0f) + bo[0];
  }
}

// ---------------- launch ----------------

extern "C" void kernel_launch(void* const* d_in, const int* in_sizes, int n_in,
                              void* d_out, int out_size, void* d_ws, size_t ws_size,
                              hipStream_t stream) {
  const float* x     = (const float*)d_in[0];
  const int*   ei    = (const int*)d_in[1];   // [2, E]: src then dst
  const int*   batch = (const int*)d_in[2];
  const float* W1    = (const float*)d_in[3];
  const float* b1    = (const float*)d_in[4];
  const float* W2    = (const float*)d_in[5];
  const float* b2    = (const float*)d_in[6];
  const float* Wo    = (const float*)d_in[7];
  const float* bo    = (const float*)d_in[8];
  float* out = (float*)d_out;

  const int* src = ei;
  const int* dst = ei + N_EDGES;

  char* w = (char*)d_ws;
  float* gaccP   = (float*)w;  w += (size_t)NCOPY * N_GRAPHS * 4;   // zeroed
  size_t zero_bytes = (size_t)(w - (char*)d_ws);
  int*   degcnt  = (int*)w;    w += (size_t)N_NODES * 4;            // written by k_bdeg
  int*   gcnt    = (int*)w;    w += (size_t)N_GRAPHS * 4;
  int*   row_ptr = (int*)w;    w += (size_t)(N_NODES + 4) * 4;
  int*   blocksum= (int*)w;    w += 128 * 4;
  int*   blockoff= (int*)w;    w += 128 * 4;
  int*   cnt     = (int*)w;    w += (size_t)ABLK * NBKT * 4;        // 1.0 MB
  int*   boff    = (int*)w;    w += (size_t)ABLK * NBKT * 4;        // 1.0 MB
  int*   btot    = (int*)w;    w += (size_t)(NBKT + 8) * 4;
  int*   bbase   = (int*)w;    w += (size_t)(NBKT + 8) * 4;
  int*   col     = (int*)w;    w += (size_t)PADCAP * 4;
  float* dis     = (float*)w;  w += (size_t)N_NODES * 4;
  u16*   hs1     = (u16*)w;    w += (size_t)(N_NODES + 1) * EMB * 2;  // +1 zero row
  u16*   out1    = (u16*)w;    w += (size_t)N_NODES * EMB * 2;        // 6.4 MB
  u32*   binbuf  = (u32*)out1;  // alias: binbuf dead before agg1 writes out1
  u16*   hs2     = hs1;         // hs1 dead after agg1; zero row persists

  const int NB  = (N_NODES + 255) / 256;    // 391
  const int SB  = (N_NODES + 1023) / 1024;  // 98
  const int GB  = (NTILE * 64 + 255) / 256; // 1563 MFMA blocks
  const int AB2 = N_NODES / 8;              // 12500 two-node-per-wave blocks

  (void)hipMemsetAsync(d_ws, 0, zero_bytes, stream);

  // bin pipeline (produces binbuf + degree histogram)
  k_binA<<<ABLK, 256, 0, stream>>>(dst, cnt);
  k_binscanA<<<NBKT, 256, 0, stream>>>(cnt, boff, btot);
  k_binscanB<<<1, 256, 0, stream>>>(btot, bbase);
  k_binscat<<<ABLK, 256, 0, stream>>>(src, dst, boff, bbase, binbuf);
  k_bdeg<<<NBKT, 256, 0, stream>>>(binbuf, bbase, degcnt);

  k_node_init<<<NB, 256, 0, stream>>>(degcnt, dis, hs1);
  k_gcnt<<<1, 512, 0, stream>>>(batch, gcnt);
  k_scanA<<<SB, 256, 0, stream>>>(degcnt, blocksum);
  k_scanB<<<1, 128, 0, stream>>>(blocksum, blockoff, row_ptr + N_NODES, SB);
  k_scanC<<<SB, 256, 0, stream>>>(degcnt, blockoff, row_ptr);
  k_fillB<<<NBKT, 256, 0, stream>>>(binbuf, bbase, row_ptr, col);

  k_gemm1<<<GB, 256, 0, stream>>>(x, W1, dis, hs1);
  k_agg1<<<AB2, 256, 0, stream>>>(hs1, row_ptr, col, dis, b1, out1);
  k_gemm2<<<GB, 256, 0, stream>>>(out1, W2, dis, hs2);
  k_agg2pool<<<AB2, 256, 0, stream>>>(hs2, row_ptr, col, dis, b2, Wo, batch, gaccP);
  k_finalize<<<2, 256, 0, stream>>>(gaccP, gcnt, bo, out);
}